// Round 9
// baseline (441.069 us; speedup 1.0000x reference)
//
#include <hip/hip_runtime.h>
#include <hip/hip_bf16.h>

#define N_NODES 100000
#define N_EDGES 1600000
#define IN_DIM 128
#define HID 64
#define N_GRAPHS 64
#define OUT_DIM 2

#define NB_BUCKETS ((N_NODES + 255) / 256)   // 391 buckets of 256 nodes
#define CHUNK 4096
#define NCHUNKS ((N_EDGES + CHUNK - 1) / CHUNK)  // 391
#define ARENA_CAP 6144   // per-bucket arena slots; mean 4092, sigma 64 -> +32 sigma

// ---------------- bf16 pack/unpack (RNE) ----------------

__device__ inline unsigned f2bf_rne(float f) {
    unsigned u = __float_as_uint(f);
    u += 0x7FFFu + ((u >> 16) & 1u);
    return u >> 16;
}
__device__ inline unsigned pack2(float lo, float hi) {
    return f2bf_rne(lo) | (f2bf_rne(hi) << 16);
}
__device__ inline float bf_lo(unsigned w) { return __uint_as_float(w << 16); }
__device__ inline float bf_hi(unsigned w) { return __uint_as_float(w & 0xFFFF0000u); }
__device__ inline float2 bf_pair(unsigned w) {
    return make_float2(bf_lo(w), bf_hi(w));
}
__device__ inline void acc2(float2& a, float2 b) { a.x += b.x; a.y += b.y; }

// ---------------- edge bucketing (single-pass arena scatter) ----------------

__global__ void kb_scan(const int* __restrict__ bcount, int* __restrict__ bbase) {
    int lane = threadIdx.x;
    int carry = 0;
    for (int c = 0; c < (NB_BUCKETS + 63) / 64; ++c) {
        int idx = c * 64 + lane;
        int v = (idx < NB_BUCKETS) ? bcount[idx] : 0;
        int orig = v;
        for (int d = 1; d < 64; d <<= 1) {
            int u = __shfl_up(v, d);
            if (lane >= d) v += u;
        }
        if (idx < NB_BUCKETS) bbase[idx] = v - orig + carry;
        carry += __shfl(v, 63);
    }
    if (lane == 0) bbase[NB_BUCKETS] = carry;
}

__global__ __launch_bounds__(256) void kb_scatter(const int* __restrict__ src,
                                                  const int* __restrict__ dst,
                                                  int* __restrict__ bcount,
                                                  unsigned* __restrict__ arena) {
    __shared__ unsigned staged[CHUNK];            // 16 KB
    __shared__ unsigned short sbuck[CHUNK];       // 8 KB
    __shared__ int hist[NB_BUCKETS];
    __shared__ int lofs[NB_BUCKETS];
    __shared__ int lcur[NB_BUCKETS];
    __shared__ int gbase[NB_BUCKETS];
    int t = threadIdx.x;
    int lane = t & 63, wv = t >> 6;
    for (int i = t; i < NB_BUCKETS; i += 256) hist[i] = 0;
    __syncthreads();
    int chunk0 = blockIdx.x * CHUNK;
    int cN = min(CHUNK, N_EDGES - chunk0);
    for (int i = t; i < cN; i += 256) atomicAdd(&hist[dst[chunk0 + i] >> 8], 1);
    __syncthreads();
    if (wv == 0) {  // exclusive scan hist -> lofs
        int carry = 0;
        for (int c = 0; c < (NB_BUCKETS + 63) / 64; ++c) {
            int idx = c * 64 + lane;
            int v = (idx < NB_BUCKETS) ? hist[idx] : 0;
            int orig = v;
            for (int d = 1; d < 64; d <<= 1) {
                int u = __shfl_up(v, d);
                if (lane >= d) v += u;
            }
            if (idx < NB_BUCKETS) lofs[idx] = v - orig + carry;
            carry += __shfl(v, 63);
        }
    }
    __syncthreads();
    for (int i = t; i < NB_BUCKETS; i += 256) {
        lcur[i] = lofs[i];
        gbase[i] = hist[i] ? (atomicAdd(&bcount[i], hist[i]) + i * ARENA_CAP) : 0;
    }
    __syncthreads();
    for (int i = t; i < cN; i += 256) {  // stage bucket-major in LDS
        int e = chunk0 + i;
        int d = dst[e];
        int b = d >> 8;
        int lp = atomicAdd(&lcur[b], 1);
        staged[lp] = ((unsigned)src[e] << 8) | (unsigned)(d & 255);
        sbuck[lp] = (unsigned short)b;
    }
    __syncthreads();
    for (int p = t; p < cN; p += 256) {  // coalesced copy-out
        int b = sbuck[p];
        arena[gbase[b] + (p - lofs[b])] = staged[p];
    }
}

__global__ __launch_bounds__(256) void k_bfin(const unsigned* __restrict__ arena,
                                              const int* __restrict__ bbase,
                                              int* __restrict__ ssrc,
                                              int* __restrict__ off,
                                              float* __restrict__ dis) {
    __shared__ int cnt[256];
    __shared__ int lofs[256];
    __shared__ int lcur[256];
    int t = threadIdx.x;
    int lane = t & 63, wv = t >> 6;
    cnt[t] = 0;
    __syncthreads();
    int b = blockIdx.x;
    int lo = bbase[b];
    int cntB = bbase[b + 1] - lo;
    const unsigned* ap = arena + (size_t)b * ARENA_CAP;
    for (int e = t; e < cntB; e += 256) atomicAdd(&cnt[ap[e] & 255], 1);
    __syncthreads();
    if (wv == 0) {
        int carry = 0;
#pragma unroll
        for (int c = 0; c < 4; ++c) {
            int idx = c * 64 + lane;
            int v = cnt[idx];
            int orig = v;
            for (int d = 1; d < 64; d <<= 1) {
                int u = __shfl_up(v, d);
                if (lane >= d) v += u;
            }
            lofs[idx] = v - orig + carry;
            carry += __shfl(v, 63);
        }
    }
    __syncthreads();
    lcur[t] = lofs[t];
    int node = b * 256 + t;
    if (node < N_NODES) {
        off[node] = lo + lofs[t];
        dis[node] = rsqrtf((float)cnt[t] + 1.0f);  // +1 = self-loop
    }
    if (b == NB_BUCKETS - 1 && t == 0) off[N_NODES] = N_EDGES;
    __syncthreads();
    for (int e = t; e < cntB; e += 256) {
        unsigned pk = ap[e];
        int p = atomicAdd(&lcur[pk & 255u], 1);
        ssrc[lo + p] = (int)(pk >> 8);
    }
}

// ---------------- weight transpose + bf16 cast (once per launch) -----------

__global__ __launch_bounds__(256) void k_wprep(const float* __restrict__ W1,
                                               const float* __restrict__ W2,
                                               const float* __restrict__ W3,
                                               unsigned short* __restrict__ Wt1,
                                               unsigned short* __restrict__ Wt2,
                                               unsigned short* __restrict__ Wt3) {
    int t = blockIdx.x * 256 + threadIdx.x;
    if (t < 64 * 128) {  // Wt1[n][k] = bf16(W1[k][n]), n<64, k<128
        int n = t >> 7, k = t & 127;
        Wt1[t] = (unsigned short)f2bf_rne(W1[k * 64 + n]);
    }
    if (t < 64 * 64) {   // Wt2/Wt3[n][k], n<64, k<64
        int n = t >> 6, k = t & 63;
        Wt2[t] = (unsigned short)f2bf_rne(W2[k * 64 + n]);
        Wt3[t] = (unsigned short)f2bf_rne(W3[k * 64 + n]);
    }
}

// ---------------- conv GEMM: MFMA bf16, g16 = bf16(dis * A@W) ---------------
// block = 256 thr / 4 waves; tile 64 rows x 64 cols; mfma_f32_16x16x32_bf16.
// A layout: A[m=lane&15][k=quad*8+j]; B from Wt[n][k]: n=lane&15,k=quad*8+j;
// C/D: col=lane&15, row=quad*4+reg  (guide section 3, HW-verified m89/m91).
template <int K, bool AF32>
__global__ __launch_bounds__(256) void k_gemm(const void* __restrict__ Ain,
                                              const unsigned short* __restrict__ Wt,
                                              const float* __restrict__ dis,
                                              unsigned* __restrict__ g16) {
    constexpr int PITCH = K + 8;  // shorts; keeps rows 16B-aligned
    constexpr int ABYTES = 2 * 64 * PITCH * 2;
    constexpr int CBYTES = 64 * 68 * 4;
    constexpr int SMEM = ABYTES > CBYTES ? ABYTES : CBYTES;
    __shared__ __align__(16) char smem[SMEM];
    short* As = (short*)smem;
    short* Bs = As + 64 * PITCH;
    float* Cs = (float*)smem;   // overlays As/Bs after MFMA phase
    constexpr int CP = 68;

    int t = threadIdx.x, lane = t & 63, w = t >> 6;
    int row0 = blockIdx.x * 64;

    constexpr int UN = 64 * (K / 8);  // 16B units per 64xK tile
#pragma unroll
    for (int u = t; u < UN; u += 256) {  // stage A (cast f32->bf16 if needed)
        int r = u / (K / 8), c = u % (K / 8);
        int grow = row0 + r;
        grow = grow < N_NODES ? grow : N_NODES - 1;
        uint4 o;
        if (AF32) {
            const float* Ap = (const float*)Ain + (size_t)grow * K + c * 8;
            float4 f0 = *(const float4*)Ap;
            float4 f1 = *(const float4*)(Ap + 4);
            o.x = pack2(f0.x, f0.y); o.y = pack2(f0.z, f0.w);
            o.z = pack2(f1.x, f1.y); o.w = pack2(f1.z, f1.w);
        } else {
            o = ((const uint4*)Ain)[(size_t)grow * (K / 8) + c];
        }
        *(uint4*)&As[r * PITCH + c * 8] = o;
    }
#pragma unroll
    for (int u = t; u < UN; u += 256) {  // stage B = Wt (already bf16, [n][K])
        int n = u / (K / 8), c = u % (K / 8);
        *(uint4*)&Bs[n * PITCH + c * 8] = *(const uint4*)&Wt[n * K + c * 8];
    }
    __syncthreads();

    using frag = __attribute__((ext_vector_type(8))) short;
    using fragc = __attribute__((ext_vector_type(4))) float;
    fragc z = {0.f, 0.f, 0.f, 0.f};
    fragc acc[4] = {z, z, z, z};
    int m = lane & 15, quad = lane >> 4;
#pragma unroll
    for (int ks = 0; ks < K / 32; ++ks) {
        frag a = *(frag*)&As[(w * 16 + m) * PITCH + ks * 32 + quad * 8];
#pragma unroll
        for (int nt = 0; nt < 4; ++nt) {
            frag b = *(frag*)&Bs[(nt * 16 + m) * PITCH + ks * 32 + quad * 8];
            acc[nt] = __builtin_amdgcn_mfma_f32_16x16x32_bf16(a, b, acc[nt], 0, 0, 0);
        }
    }
    __syncthreads();  // done reading As/Bs; reuse as Cs
#pragma unroll
    for (int nt = 0; nt < 4; ++nt)
#pragma unroll
        for (int reg = 0; reg < 4; ++reg)
            Cs[(w * 16 + quad * 4 + reg) * CP + nt * 16 + m] = acc[nt][reg];
    __syncthreads();

    {   // epilogue: thread -> (row, 16-col segment); scale by dis, pack bf16
        int r = t >> 2, c0 = (t & 3) * 16;
        int grow = row0 + r;
        if (grow < N_NODES) {
            float dr = dis[grow];
            const float* cp = &Cs[r * CP + c0];
            uint4 o0, o1;
            o0.x = pack2(cp[0] * dr, cp[1] * dr);
            o0.y = pack2(cp[2] * dr, cp[3] * dr);
            o0.z = pack2(cp[4] * dr, cp[5] * dr);
            o0.w = pack2(cp[6] * dr, cp[7] * dr);
            o1.x = pack2(cp[8] * dr, cp[9] * dr);
            o1.y = pack2(cp[10] * dr, cp[11] * dr);
            o1.z = pack2(cp[12] * dr, cp[13] * dr);
            o1.w = pack2(cp[14] * dr, cp[15] * dr);
            ((uint4*)g16)[(size_t)grow * 8 + (c0 >> 3)] = o0;
            ((uint4*)g16)[(size_t)grow * 8 + (c0 >> 3) + 1] = o1;
        }
    }
}

// ---------------- aggregate: 16 edge slots x 4 lanes x 32B, bf16 in/out -----
// h16[i,:] = bf16( act( dis[i] * (g16[i,:] + sum_e g16[ssrc[e],:]) + b ) )
template <bool RELU>
__global__ __launch_bounds__(256) void k_aggr(const unsigned* __restrict__ g16,
                                              const int* __restrict__ off,
                                              const int* __restrict__ ssrc,
                                              const float* __restrict__ dis,
                                              const float* __restrict__ bias,
                                              unsigned* __restrict__ h16) {
    int row = blockIdx.x * 4 + (threadIdx.x >> 6);
    int lane = threadIdx.x & 63;
    int sub = lane >> 2;   // edge slot 0..15
    int li = lane & 3;     // 32B segment (features [li*16, li*16+16))
    if (row >= N_NODES) return;
    const uint4* g4 = (const uint4*)g16;   // row = 8 uint4
    float2 acc[8];
#pragma unroll
    for (int j = 0; j < 8; ++j) acc[j] = make_float2(0.f, 0.f);
    int lo = off[row], hi = off[row + 1];
    for (int e = lo + sub; e < hi; e += 16) {
        unsigned s = (unsigned)ssrc[e];
        unsigned base = s * 8u + (unsigned)li * 2u;
        uint4 v0 = g4[base];
        uint4 v1 = g4[base + 1];
        acc2(acc[0], bf_pair(v0.x)); acc2(acc[1], bf_pair(v0.y));
        acc2(acc[2], bf_pair(v0.z)); acc2(acc[3], bf_pair(v0.w));
        acc2(acc[4], bf_pair(v1.x)); acc2(acc[5], bf_pair(v1.y));
        acc2(acc[6], bf_pair(v1.z)); acc2(acc[7], bf_pair(v1.w));
    }
    // combine 16 edge slots (lane bits 2..5)
#pragma unroll
    for (int d = 4; d <= 32; d <<= 1) {
#pragma unroll
        for (int j = 0; j < 8; ++j) {
            acc[j].x += __shfl_xor(acc[j].x, d);
            acc[j].y += __shfl_xor(acc[j].y, d);
        }
    }
    if (sub == 0) {  // lanes 0..3 write the row
        unsigned base = (unsigned)row * 8u + (unsigned)li * 2u;
        uint4 s0 = g4[base], s1 = g4[base + 1];
        float2 sp[8] = {bf_pair(s0.x), bf_pair(s0.y), bf_pair(s0.z), bf_pair(s0.w),
                        bf_pair(s1.x), bf_pair(s1.y), bf_pair(s1.z), bf_pair(s1.w)};
        float dr = dis[row];
        const float4* bp = (const float4*)bias + li * 4;
        float4 b0 = bp[0], b1 = bp[1], b2 = bp[2], b3 = bp[3];
        float bb[16] = {b0.x, b0.y, b0.z, b0.w, b1.x, b1.y, b1.z, b1.w,
                        b2.x, b2.y, b2.z, b2.w, b3.x, b3.y, b3.z, b3.w};
        float o[16];
#pragma unroll
        for (int j = 0; j < 8; ++j) {
            o[2 * j]     = dr * (acc[j].x + sp[j].x) + bb[2 * j];
            o[2 * j + 1] = dr * (acc[j].y + sp[j].y) + bb[2 * j + 1];
        }
        if (RELU) {
#pragma unroll
            for (int j = 0; j < 16; ++j) o[j] = fmaxf(o[j], 0.f);
        }
        uint4 w0, w1;
        w0.x = pack2(o[0], o[1]);   w0.y = pack2(o[2], o[3]);
        w0.z = pack2(o[4], o[5]);   w0.w = pack2(o[6], o[7]);
        w1.x = pack2(o[8], o[9]);   w1.y = pack2(o[10], o[11]);
        w1.z = pack2(o[12], o[13]); w1.w = pack2(o[14], o[15]);
        ((uint4*)h16)[base] = w0;
        ((uint4*)h16)[base + 1] = w1;
    }
}

// ---------------- pooling + classifier ----------------

__global__ __launch_bounds__(256) void k_pool1(const unsigned short* __restrict__ h16,
                                               const int* __restrict__ batch,
                                               float* __restrict__ sums) {
    int lane = threadIdx.x & 63, wv = threadIdx.x >> 6;
    int node0 = blockIdx.x * 256 + wv * 64;
    int node1 = min(node0 + 64, N_NODES);
    float acc = 0.f;
    int cur = -1;
    for (int i = node0; i < node1; ++i) {
        int bi = batch[i];
        if (bi != cur) {
            if (cur >= 0) atomicAdd(&sums[cur * HID + lane], acc);
            acc = 0.f;
            cur = bi;
        }
        unsigned u = h16[(size_t)i * HID + lane];
        acc += __uint_as_float(u << 16);
    }
    if (cur >= 0) atomicAdd(&sums[cur * HID + lane], acc);
}

__device__ inline int lower_bound_batch(const int* batch, int key) {
    int lo = 0, hi = N_NODES;
    while (lo < hi) {
        int mid = (lo + hi) >> 1;
        if (batch[mid] < key) lo = mid + 1;
        else hi = mid;
    }
    return lo;
}

__global__ __launch_bounds__(256) void k_cls(const float* __restrict__ sums,
                                             const int* __restrict__ batch,
                                             const float* __restrict__ Wc1,
                                             const float* __restrict__ bc1,
                                             const float* __restrict__ Wc2,
                                             const float* __restrict__ bc2,
                                             float* __restrict__ out) {
    __shared__ float pooled[N_GRAPHS][HID];
    __shared__ float hc[N_GRAPHS][HID / 2];
    __shared__ float cnts[N_GRAPHS];
    int t = threadIdx.x;
    if (t < N_GRAPHS) {
        int lo = lower_bound_batch(batch, t);
        int hi = lower_bound_batch(batch, t + 1);
        cnts[t] = fmaxf((float)(hi - lo), 1.0f);
    }
    __syncthreads();
    for (int idx = t; idx < N_GRAPHS * HID; idx += 256) {
        int gi = idx >> 6;
        pooled[gi][idx & 63] = sums[idx] / cnts[gi];
    }
    __syncthreads();
    for (int idx = t; idx < N_GRAPHS * (HID / 2); idx += 256) {
        int gi = idx >> 5, f = idx & 31;
        float a = bc1[f];
#pragma unroll
        for (int k = 0; k < HID; ++k) a = fmaf(pooled[gi][k], Wc1[k * (HID / 2) + f], a);
        hc[gi][f] = fmaxf(a, 0.f);
    }
    __syncthreads();
    for (int idx = t; idx < N_GRAPHS * OUT_DIM; idx += 256) {
        int gi = idx >> 1, f = idx & 1;
        float a = bc2[f];
#pragma unroll
        for (int k = 0; k < HID / 2; ++k) a = fmaf(hc[gi][k], Wc2[k * OUT_DIM + f], a);
        out[gi * OUT_DIM + f] = a;
    }
}

// ---------------- launch ----------------

extern "C" void kernel_launch(void* const* d_in, const int* in_sizes, int n_in,
                              void* d_out, int out_size, void* d_ws, size_t ws_size,
                              hipStream_t stream) {
    const float* x    = (const float*)d_in[0];
    const int*   eidx = (const int*)d_in[1];
    const int*   batch= (const int*)d_in[2];
    const float* W1 = (const float*)d_in[3];  const float* b1 = (const float*)d_in[4];
    const float* W2 = (const float*)d_in[5];  const float* b2 = (const float*)d_in[6];
    const float* W3 = (const float*)d_in[7];  const float* b3 = (const float*)d_in[8];
    const float* Wc1 = (const float*)d_in[9];  const float* bc1 = (const float*)d_in[10];
    const float* Wc2 = (const float*)d_in[11]; const float* bc2 = (const float*)d_in[12];
    float* out = (float*)d_out;

    const int* esrc = eidx;
    const int* edst = eidx + N_EDGES;

    size_t o = 0;
    auto alloc = [&](size_t bytes) {
        void* p = (char*)d_ws + o;
        o += (bytes + 255) & ~(size_t)255;
        return p;
    };
    int*            bcount = (int*)alloc((size_t)NB_BUCKETS * 4);
    int*            bbase  = (int*)alloc((size_t)(NB_BUCKETS + 1) * 4);
    float*          dis    = (float*)alloc((size_t)N_NODES * 4);
    unsigned*       arena  = (unsigned*)alloc((size_t)NB_BUCKETS * ARENA_CAP * 4);
    int*            ssrc   = (int*)alloc((size_t)N_EDGES * 4);
    int*            off    = (int*)alloc((size_t)(N_NODES + 1) * 4);
    unsigned*       g16    = (unsigned*)alloc((size_t)N_NODES * HID * 2);
    unsigned*       h16    = (unsigned*)alloc((size_t)N_NODES * HID * 2);
    unsigned short* Wt1    = (unsigned short*)alloc((size_t)64 * 128 * 2);
    unsigned short* Wt2    = (unsigned short*)alloc((size_t)64 * 64 * 2);
    unsigned short* Wt3    = (unsigned short*)alloc((size_t)64 * 64 * 2);
    float*          sums   = (float*)alloc((size_t)N_GRAPHS * HID * 4);
    (void)ws_size;

    const int TB = 256;
    int gridG = (N_NODES + 63) / 64;
    int gridR = (N_NODES + 3) / 4;

    // 1) preprocessing: arena bucketing -> CSR; weight transpose/cast
    hipMemsetAsync(bcount, 0, (size_t)NB_BUCKETS * 4, stream);
    hipMemsetAsync(sums, 0, (size_t)N_GRAPHS * HID * 4, stream);
    k_wprep<<<32, TB, 0, stream>>>(W1, W2, W3, Wt1, Wt2, Wt3);
    kb_scatter<<<NCHUNKS, TB, 0, stream>>>(esrc, edst, bcount, arena);
    kb_scan<<<1, 64, 0, stream>>>(bcount, bbase);
    k_bfin<<<NB_BUCKETS, TB, 0, stream>>>(arena, bbase, ssrc, off, dis);

    // 2) conv1 (A = x f32, cast in staging)
    k_gemm<IN_DIM, true><<<gridG, TB, 0, stream>>>(x, Wt1, dis, g16);
    k_aggr<true><<<gridR, TB, 0, stream>>>(g16, off, ssrc, dis, b1, h16);

    // 3) conv2 (A = h16 bf16)
    k_gemm<HID, false><<<gridG, TB, 0, stream>>>(h16, Wt2, dis, g16);
    k_aggr<true><<<gridR, TB, 0, stream>>>(g16, off, ssrc, dis, b2, h16);

    // 4) conv3 (no relu)
    k_gemm<HID, false><<<gridG, TB, 0, stream>>>(h16, Wt3, dis, g16);
    k_aggr<false><<<gridR, TB, 0, stream>>>(g16, off, ssrc, dis, b3, h16);

    // 5) pool + classifier
    k_pool1<<<NB_BUCKETS, TB, 0, stream>>>((const unsigned short*)h16, batch, sums);
    k_cls<<<1, TB, 0, stream>>>(sums, batch, Wc1, bc1, Wc2, bc2, out);
}

// Round 10
// 365.252 us; speedup vs baseline: 1.2076x; 1.2076x over previous
//
#include <hip/hip_runtime.h>
#include <hip/hip_bf16.h>

#define N_NODES 100000
#define N_EDGES 1600000
#define IN_DIM 128
#define HID 64
#define N_GRAPHS 64
#define OUT_DIM 2

#define NB_BUCKETS ((N_NODES + 255) / 256)   // 391 buckets of 256 nodes
#define CHUNK 4096
#define NCHUNKS ((N_EDGES + CHUNK - 1) / CHUNK)  // 391
#define ARENA_CAP 6144   // per-bucket arena slots; mean 4092, sigma 64 -> +32 sigma

// ---------------- bf16 pack/unpack (RNE) ----------------

__device__ inline unsigned f2bf_rne(float f) {
    unsigned u = __float_as_uint(f);
    u += 0x7FFFu + ((u >> 16) & 1u);
    return u >> 16;
}
__device__ inline unsigned pack2(float lo, float hi) {
    return f2bf_rne(lo) | (f2bf_rne(hi) << 16);
}
__device__ inline float bf_lo(unsigned w) { return __uint_as_float(w << 16); }
__device__ inline float bf_hi(unsigned w) { return __uint_as_float(w & 0xFFFF0000u); }
__device__ inline float2 bf_pair(unsigned w) {
    return make_float2(bf_lo(w), bf_hi(w));
}
__device__ inline void acc2(float2& a, float2 b) { a.x += b.x; a.y += b.y; }

// ---------------- edge bucketing (single-pass arena scatter) ----------------

__global__ void kb_scan(const int* __restrict__ bcount, int* __restrict__ bbase) {
    int lane = threadIdx.x;
    int carry = 0;
    for (int c = 0; c < (NB_BUCKETS + 63) / 64; ++c) {
        int idx = c * 64 + lane;
        int v = (idx < NB_BUCKETS) ? bcount[idx] : 0;
        int orig = v;
        for (int d = 1; d < 64; d <<= 1) {
            int u = __shfl_up(v, d);
            if (lane >= d) v += u;
        }
        if (idx < NB_BUCKETS) bbase[idx] = v - orig + carry;
        carry += __shfl(v, 63);
    }
    if (lane == 0) bbase[NB_BUCKETS] = carry;
}

__global__ __launch_bounds__(256) void kb_scatter(const int* __restrict__ src,
                                                  const int* __restrict__ dst,
                                                  int* __restrict__ bcount,
                                                  unsigned* __restrict__ arena) {
    __shared__ unsigned staged[CHUNK];            // 16 KB
    __shared__ unsigned short sbuck[CHUNK];       // 8 KB
    __shared__ int hist[NB_BUCKETS];
    __shared__ int lofs[NB_BUCKETS];
    __shared__ int lcur[NB_BUCKETS];
    __shared__ int gbase[NB_BUCKETS];
    int t = threadIdx.x;
    int lane = t & 63, wv = t >> 6;
    for (int i = t; i < NB_BUCKETS; i += 256) hist[i] = 0;
    __syncthreads();
    int chunk0 = blockIdx.x * CHUNK;
    int cN = min(CHUNK, N_EDGES - chunk0);
    for (int i = t; i < cN; i += 256) atomicAdd(&hist[dst[chunk0 + i] >> 8], 1);
    __syncthreads();
    if (wv == 0) {  // exclusive scan hist -> lofs
        int carry = 0;
        for (int c = 0; c < (NB_BUCKETS + 63) / 64; ++c) {
            int idx = c * 64 + lane;
            int v = (idx < NB_BUCKETS) ? hist[idx] : 0;
            int orig = v;
            for (int d = 1; d < 64; d <<= 1) {
                int u = __shfl_up(v, d);
                if (lane >= d) v += u;
            }
            if (idx < NB_BUCKETS) lofs[idx] = v - orig + carry;
            carry += __shfl(v, 63);
        }
    }
    __syncthreads();
    for (int i = t; i < NB_BUCKETS; i += 256) {
        lcur[i] = lofs[i];
        gbase[i] = hist[i] ? (atomicAdd(&bcount[i], hist[i]) + i * ARENA_CAP) : 0;
    }
    __syncthreads();
    for (int i = t; i < cN; i += 256) {  // stage bucket-major in LDS
        int e = chunk0 + i;
        int d = dst[e];
        int b = d >> 8;
        int lp = atomicAdd(&lcur[b], 1);
        staged[lp] = ((unsigned)src[e] << 8) | (unsigned)(d & 255);
        sbuck[lp] = (unsigned short)b;
    }
    __syncthreads();
    for (int p = t; p < cN; p += 256) {  // coalesced copy-out
        int b = sbuck[p];
        arena[gbase[b] + (p - lofs[b])] = staged[p];
    }
}

__global__ __launch_bounds__(256) void k_bfin(const unsigned* __restrict__ arena,
                                              const int* __restrict__ bbase,
                                              int* __restrict__ ssrc,
                                              int* __restrict__ off,
                                              float* __restrict__ dis) {
    __shared__ int cnt[256];
    __shared__ int lofs[256];
    __shared__ int lcur[256];
    int t = threadIdx.x;
    int lane = t & 63, wv = t >> 6;
    cnt[t] = 0;
    __syncthreads();
    int b = blockIdx.x;
    int lo = bbase[b];
    int cntB = bbase[b + 1] - lo;
    const unsigned* ap = arena + (size_t)b * ARENA_CAP;
    for (int e = t; e < cntB; e += 256) atomicAdd(&cnt[ap[e] & 255], 1);
    __syncthreads();
    if (wv == 0) {
        int carry = 0;
#pragma unroll
        for (int c = 0; c < 4; ++c) {
            int idx = c * 64 + lane;
            int v = cnt[idx];
            int orig = v;
            for (int d = 1; d < 64; d <<= 1) {
                int u = __shfl_up(v, d);
                if (lane >= d) v += u;
            }
            lofs[idx] = v - orig + carry;
            carry += __shfl(v, 63);
        }
    }
    __syncthreads();
    lcur[t] = lofs[t];
    int node = b * 256 + t;
    if (node < N_NODES) {
        off[node] = lo + lofs[t];
        dis[node] = rsqrtf((float)cnt[t] + 1.0f);  // +1 = self-loop
    }
    if (b == NB_BUCKETS - 1 && t == 0) off[N_NODES] = N_EDGES;
    __syncthreads();
    for (int e = t; e < cntB; e += 256) {
        unsigned pk = ap[e];
        int p = atomicAdd(&lcur[pk & 255u], 1);
        ssrc[lo + p] = (int)(pk >> 8);
    }
}

// ---------------- weight transpose + bf16 cast (once per launch) -----------

__global__ __launch_bounds__(256) void k_wprep(const float* __restrict__ W1,
                                               const float* __restrict__ W2,
                                               const float* __restrict__ W3,
                                               unsigned short* __restrict__ Wt1,
                                               unsigned short* __restrict__ Wt2,
                                               unsigned short* __restrict__ Wt3) {
    int t = blockIdx.x * 256 + threadIdx.x;
    if (t < 64 * 128) {  // Wt1[n][k] = bf16(W1[k][n]), n<64, k<128
        int n = t >> 7, k = t & 127;
        Wt1[t] = (unsigned short)f2bf_rne(W1[k * 64 + n]);
    }
    if (t < 64 * 64) {   // Wt2/Wt3[n][k], n<64, k<64
        int n = t >> 6, k = t & 63;
        Wt2[t] = (unsigned short)f2bf_rne(W2[k * 64 + n]);
        Wt3[t] = (unsigned short)f2bf_rne(W3[k * 64 + n]);
    }
}

// ---------------- conv GEMM: MFMA bf16, g16 = bf16(dis * A@W) ---------------
// block = 256 thr / 4 waves; tile 64 rows x 64 cols; mfma_f32_16x16x32_bf16.
template <int K, bool AF32>
__global__ __launch_bounds__(256) void k_gemm(const void* __restrict__ Ain,
                                              const unsigned short* __restrict__ Wt,
                                              const float* __restrict__ dis,
                                              unsigned* __restrict__ g16) {
    constexpr int PITCH = K + 8;  // shorts; keeps rows 16B-aligned
    constexpr int ABYTES = 2 * 64 * PITCH * 2;
    constexpr int CBYTES = 64 * 68 * 4;
    constexpr int SMEM = ABYTES > CBYTES ? ABYTES : CBYTES;
    __shared__ __align__(16) char smem[SMEM];
    short* As = (short*)smem;
    short* Bs = As + 64 * PITCH;
    float* Cs = (float*)smem;   // overlays As/Bs after MFMA phase
    constexpr int CP = 68;

    int t = threadIdx.x, lane = t & 63, w = t >> 6;
    int row0 = blockIdx.x * 64;

    constexpr int UN = 64 * (K / 8);  // 16B units per 64xK tile
#pragma unroll
    for (int u = t; u < UN; u += 256) {  // stage A (cast f32->bf16 if needed)
        int r = u / (K / 8), c = u % (K / 8);
        int grow = row0 + r;
        grow = grow < N_NODES ? grow : N_NODES - 1;
        uint4 o;
        if (AF32) {
            const float* Ap = (const float*)Ain + (size_t)grow * K + c * 8;
            float4 f0 = *(const float4*)Ap;
            float4 f1 = *(const float4*)(Ap + 4);
            o.x = pack2(f0.x, f0.y); o.y = pack2(f0.z, f0.w);
            o.z = pack2(f1.x, f1.y); o.w = pack2(f1.z, f1.w);
        } else {
            o = ((const uint4*)Ain)[(size_t)grow * (K / 8) + c];
        }
        *(uint4*)&As[r * PITCH + c * 8] = o;
    }
#pragma unroll
    for (int u = t; u < UN; u += 256) {  // stage B = Wt (already bf16, [n][K])
        int n = u / (K / 8), c = u % (K / 8);
        *(uint4*)&Bs[n * PITCH + c * 8] = *(const uint4*)&Wt[n * K + c * 8];
    }
    __syncthreads();

    using frag = __attribute__((ext_vector_type(8))) short;
    using fragc = __attribute__((ext_vector_type(4))) float;
    fragc z = {0.f, 0.f, 0.f, 0.f};
    fragc acc[4] = {z, z, z, z};
    int m = lane & 15, quad = lane >> 4;
#pragma unroll
    for (int ks = 0; ks < K / 32; ++ks) {
        frag a = *(frag*)&As[(w * 16 + m) * PITCH + ks * 32 + quad * 8];
#pragma unroll
        for (int nt = 0; nt < 4; ++nt) {
            frag b = *(frag*)&Bs[(nt * 16 + m) * PITCH + ks * 32 + quad * 8];
            acc[nt] = __builtin_amdgcn_mfma_f32_16x16x32_bf16(a, b, acc[nt], 0, 0, 0);
        }
    }
    __syncthreads();  // done reading As/Bs; reuse as Cs
#pragma unroll
    for (int nt = 0; nt < 4; ++nt)
#pragma unroll
        for (int reg = 0; reg < 4; ++reg)
            Cs[(w * 16 + quad * 4 + reg) * CP + nt * 16 + m] = acc[nt][reg];
    __syncthreads();

    {   // epilogue: thread -> (row, 16-col segment); scale by dis, pack bf16
        int r = t >> 2, c0 = (t & 3) * 16;
        int grow = row0 + r;
        if (grow < N_NODES) {
            float dr = dis[grow];
            const float* cp = &Cs[r * CP + c0];
            uint4 o0, o1;
            o0.x = pack2(cp[0] * dr, cp[1] * dr);
            o0.y = pack2(cp[2] * dr, cp[3] * dr);
            o0.z = pack2(cp[4] * dr, cp[5] * dr);
            o0.w = pack2(cp[6] * dr, cp[7] * dr);
            o1.x = pack2(cp[8] * dr, cp[9] * dr);
            o1.y = pack2(cp[10] * dr, cp[11] * dr);
            o1.z = pack2(cp[12] * dr, cp[13] * dr);
            o1.w = pack2(cp[14] * dr, cp[15] * dr);
            ((uint4*)g16)[(size_t)grow * 8 + (c0 >> 3)] = o0;
            ((uint4*)g16)[(size_t)grow * 8 + (c0 >> 3) + 1] = o1;
        }
    }
}

// ---------------- aggregate: 8 edge slots x 8 lanes x 16B, unroll 2 ---------
// h16[i,:] = bf16( act( dis[i] * (g16[i,:] + sum_e g16[ssrc[e],:]) + b ) )
template <bool RELU>
__global__ __launch_bounds__(256) void k_aggr(const unsigned* __restrict__ g16,
                                              const int* __restrict__ off,
                                              const int* __restrict__ ssrc,
                                              const float* __restrict__ dis,
                                              const float* __restrict__ bias,
                                              unsigned* __restrict__ h16) {
    int row = blockIdx.x * 4 + (threadIdx.x >> 6);
    int lane = threadIdx.x & 63;
    int sub = lane >> 3;   // edge slot 0..7
    int li = lane & 7;     // 16B segment of the 128B row
    if (row >= N_NODES) return;
    const uint4* g4 = (const uint4*)g16;   // row = 8 uint4
    float2 acc[4] = {make_float2(0.f, 0.f), make_float2(0.f, 0.f),
                     make_float2(0.f, 0.f), make_float2(0.f, 0.f)};
    int lo = off[row], hi = off[row + 1];
    int e = lo + sub;
    for (; e + 8 < hi; e += 16) {  // two edges per slot per iteration
        unsigned o0 = (unsigned)ssrc[e] * 8u + (unsigned)li;
        unsigned o1 = (unsigned)ssrc[e + 8] * 8u + (unsigned)li;
        uint4 v0 = g4[o0];
        uint4 v1 = g4[o1];
        acc2(acc[0], bf_pair(v0.x)); acc2(acc[0], bf_pair(v1.x));
        acc2(acc[1], bf_pair(v0.y)); acc2(acc[1], bf_pair(v1.y));
        acc2(acc[2], bf_pair(v0.z)); acc2(acc[2], bf_pair(v1.z));
        acc2(acc[3], bf_pair(v0.w)); acc2(acc[3], bf_pair(v1.w));
    }
    if (e < hi) {
        unsigned o = (unsigned)ssrc[e] * 8u + (unsigned)li;
        uint4 v = g4[o];
        acc2(acc[0], bf_pair(v.x));
        acc2(acc[1], bf_pair(v.y));
        acc2(acc[2], bf_pair(v.z));
        acc2(acc[3], bf_pair(v.w));
    }
    // combine the 8 edge slots (lanes differing in bits 3..5 hold same features)
#pragma unroll
    for (int d = 8; d <= 32; d <<= 1) {
#pragma unroll
        for (int j = 0; j < 4; ++j) {
            acc[j].x += __shfl_xor(acc[j].x, d);
            acc[j].y += __shfl_xor(acc[j].y, d);
        }
    }
    if (sub == 0) {  // lanes 0..7 write the row (one uint4 of packed bf16 each)
        unsigned base = (unsigned)row * 8u + (unsigned)li;
        uint4 sv = g4[base];
        float2 sp[4] = {bf_pair(sv.x), bf_pair(sv.y), bf_pair(sv.z), bf_pair(sv.w)};
        float dr = dis[row];
        float4 b0 = ((const float4*)bias)[li * 2];
        float4 b1 = ((const float4*)bias)[li * 2 + 1];
        float bb[8] = {b0.x, b0.y, b0.z, b0.w, b1.x, b1.y, b1.z, b1.w};
        float o[8];
#pragma unroll
        for (int j = 0; j < 4; ++j) {
            o[2 * j]     = dr * (acc[j].x + sp[j].x) + bb[2 * j];
            o[2 * j + 1] = dr * (acc[j].y + sp[j].y) + bb[2 * j + 1];
        }
        if (RELU) {
#pragma unroll
            for (int j = 0; j < 8; ++j) o[j] = fmaxf(o[j], 0.f);
        }
        uint4 wv;
        wv.x = pack2(o[0], o[1]);
        wv.y = pack2(o[2], o[3]);
        wv.z = pack2(o[4], o[5]);
        wv.w = pack2(o[6], o[7]);
        ((uint4*)h16)[base] = wv;
    }
}

// ---------------- pooling + classifier ----------------

__global__ __launch_bounds__(256) void k_pool1(const unsigned short* __restrict__ h16,
                                               const int* __restrict__ batch,
                                               float* __restrict__ sums) {
    int lane = threadIdx.x & 63, wv = threadIdx.x >> 6;
    int node0 = blockIdx.x * 256 + wv * 64;
    int node1 = min(node0 + 64, N_NODES);
    float acc = 0.f;
    int cur = -1;
    for (int i = node0; i < node1; ++i) {
        int bi = batch[i];
        if (bi != cur) {
            if (cur >= 0) atomicAdd(&sums[cur * HID + lane], acc);
            acc = 0.f;
            cur = bi;
        }
        unsigned u = h16[(size_t)i * HID + lane];
        acc += __uint_as_float(u << 16);
    }
    if (cur >= 0) atomicAdd(&sums[cur * HID + lane], acc);
}

__device__ inline int lower_bound_batch(const int* batch, int key) {
    int lo = 0, hi = N_NODES;
    while (lo < hi) {
        int mid = (lo + hi) >> 1;
        if (batch[mid] < key) lo = mid + 1;
        else hi = mid;
    }
    return lo;
}

__global__ __launch_bounds__(256) void k_cls(const float* __restrict__ sums,
                                             const int* __restrict__ batch,
                                             const float* __restrict__ Wc1,
                                             const float* __restrict__ bc1,
                                             const float* __restrict__ Wc2,
                                             const float* __restrict__ bc2,
                                             float* __restrict__ out) {
    __shared__ float pooled[N_GRAPHS][HID];
    __shared__ float hc[N_GRAPHS][HID / 2];
    __shared__ float cnts[N_GRAPHS];
    int t = threadIdx.x;
    if (t < N_GRAPHS) {
        int lo = lower_bound_batch(batch, t);
        int hi = lower_bound_batch(batch, t + 1);
        cnts[t] = fmaxf((float)(hi - lo), 1.0f);
    }
    __syncthreads();
    for (int idx = t; idx < N_GRAPHS * HID; idx += 256) {
        int gi = idx >> 6;
        pooled[gi][idx & 63] = sums[idx] / cnts[gi];
    }
    __syncthreads();
    for (int idx = t; idx < N_GRAPHS * (HID / 2); idx += 256) {
        int gi = idx >> 5, f = idx & 31;
        float a = bc1[f];
#pragma unroll
        for (int k = 0; k < HID; ++k) a = fmaf(pooled[gi][k], Wc1[k * (HID / 2) + f], a);
        hc[gi][f] = fmaxf(a, 0.f);
    }
    __syncthreads();
    for (int idx = t; idx < N_GRAPHS * OUT_DIM; idx += 256) {
        int gi = idx >> 1, f = idx & 1;
        float a = bc2[f];
#pragma unroll
        for (int k = 0; k < HID / 2; ++k) a = fmaf(hc[gi][k], Wc2[k * OUT_DIM + f], a);
        out[gi * OUT_DIM + f] = a;
    }
}

// ---------------- launch ----------------

extern "C" void kernel_launch(void* const* d_in, const int* in_sizes, int n_in,
                              void* d_out, int out_size, void* d_ws, size_t ws_size,
                              hipStream_t stream) {
    const float* x    = (const float*)d_in[0];
    const int*   eidx = (const int*)d_in[1];
    const int*   batch= (const int*)d_in[2];
    const float* W1 = (const float*)d_in[3];  const float* b1 = (const float*)d_in[4];
    const float* W2 = (const float*)d_in[5];  const float* b2 = (const float*)d_in[6];
    const float* W3 = (const float*)d_in[7];  const float* b3 = (const float*)d_in[8];
    const float* Wc1 = (const float*)d_in[9];  const float* bc1 = (const float*)d_in[10];
    const float* Wc2 = (const float*)d_in[11]; const float* bc2 = (const float*)d_in[12];
    float* out = (float*)d_out;

    const int* esrc = eidx;
    const int* edst = eidx + N_EDGES;

    size_t o = 0;
    auto alloc = [&](size_t bytes) {
        void* p = (char*)d_ws + o;
        o += (bytes + 255) & ~(size_t)255;
        return p;
    };
    int*            bcount = (int*)alloc((size_t)NB_BUCKETS * 4);
    int*            bbase  = (int*)alloc((size_t)(NB_BUCKETS + 1) * 4);
    float*          dis    = (float*)alloc((size_t)N_NODES * 4);
    unsigned*       arena  = (unsigned*)alloc((size_t)NB_BUCKETS * ARENA_CAP * 4);
    int*            ssrc   = (int*)alloc((size_t)N_EDGES * 4);
    int*            off    = (int*)alloc((size_t)(N_NODES + 1) * 4);
    unsigned*       g16    = (unsigned*)alloc((size_t)N_NODES * HID * 2);
    unsigned*       h16    = (unsigned*)alloc((size_t)N_NODES * HID * 2);
    unsigned short* Wt1    = (unsigned short*)alloc((size_t)64 * 128 * 2);
    unsigned short* Wt2    = (unsigned short*)alloc((size_t)64 * 64 * 2);
    unsigned short* Wt3    = (unsigned short*)alloc((size_t)64 * 64 * 2);
    float*          sums   = (float*)alloc((size_t)N_GRAPHS * HID * 4);
    (void)ws_size;

    const int TB = 256;
    int gridG = (N_NODES + 63) / 64;
    int gridR = (N_NODES + 3) / 4;

    // 1) preprocessing: arena bucketing -> CSR; weight transpose/cast
    hipMemsetAsync(bcount, 0, (size_t)NB_BUCKETS * 4, stream);
    hipMemsetAsync(sums, 0, (size_t)N_GRAPHS * HID * 4, stream);
    k_wprep<<<32, TB, 0, stream>>>(W1, W2, W3, Wt1, Wt2, Wt3);
    kb_scatter<<<NCHUNKS, TB, 0, stream>>>(esrc, edst, bcount, arena);
    kb_scan<<<1, 64, 0, stream>>>(bcount, bbase);
    k_bfin<<<NB_BUCKETS, TB, 0, stream>>>(arena, bbase, ssrc, off, dis);

    // 2) conv1 (A = x f32, cast in staging)
    k_gemm<IN_DIM, true><<<gridG, TB, 0, stream>>>(x, Wt1, dis, g16);
    k_aggr<true><<<gridR, TB, 0, stream>>>(g16, off, ssrc, dis, b1, h16);

    // 3) conv2 (A = h16 bf16)
    k_gemm<HID, false><<<gridG, TB, 0, stream>>>(h16, Wt2, dis, g16);
    k_aggr<true><<<gridR, TB, 0, stream>>>(g16, off, ssrc, dis, b2, h16);

    // 4) conv3 (no relu)
    k_gemm<HID, false><<<gridG, TB, 0, stream>>>(h16, Wt3, dis, g16);
    k_aggr<false><<<gridR, TB, 0, stream>>>(g16, off, ssrc, dis, b3, h16);

    // 5) pool + classifier
    k_pool1<<<NB_BUCKETS, TB, 0, stream>>>((const unsigned short*)h16, batch, sums);
    k_cls<<<1, TB, 0, stream>>>(sums, batch, Wc1, bc1, Wc2, bc2, out);
}

// Round 11
// 333.174 us; speedup vs baseline: 1.3238x; 1.0963x over previous
//
#include <hip/hip_runtime.h>
#include <hip/hip_bf16.h>

#define N_NODES 100000
#define N_EDGES 1600000
#define IN_DIM 128
#define HID 64
#define N_GRAPHS 64
#define OUT_DIM 2

#define NB_BUCKETS ((N_NODES + 255) / 256)   // 391 buckets of 256 nodes
#define CHUNK 4096
#define NCHUNKS ((N_EDGES + CHUNK - 1) / CHUNK)  // 391
#define ARENA_CAP 6144   // per-bucket arena slots; mean 4092, sigma 64 -> +32 sigma

// ---------------- bf16 pack/unpack (RNE) ----------------

__device__ inline unsigned f2bf_rne(float f) {
    unsigned u = __float_as_uint(f);
    u += 0x7FFFu + ((u >> 16) & 1u);
    return u >> 16;
}
__device__ inline unsigned pack2(float lo, float hi) {
    return f2bf_rne(lo) | (f2bf_rne(hi) << 16);
}
__device__ inline float bf_lo(unsigned w) { return __uint_as_float(w << 16); }
__device__ inline float bf_hi(unsigned w) { return __uint_as_float(w & 0xFFFF0000u); }
__device__ inline float2 bf_pair(unsigned w) {
    return make_float2(bf_lo(w), bf_hi(w));
}
__device__ inline void acc2(float2& a, float2 b) { a.x += b.x; a.y += b.y; }

// ---------------- edge bucketing (single-pass arena scatter) ----------------

__global__ void kb_scan(const int* __restrict__ bcount, int* __restrict__ bbase) {
    int lane = threadIdx.x;
    int carry = 0;
    for (int c = 0; c < (NB_BUCKETS + 63) / 64; ++c) {
        int idx = c * 64 + lane;
        int v = (idx < NB_BUCKETS) ? bcount[idx] : 0;
        int orig = v;
        for (int d = 1; d < 64; d <<= 1) {
            int u = __shfl_up(v, d);
            if (lane >= d) v += u;
        }
        if (idx < NB_BUCKETS) bbase[idx] = v - orig + carry;
        carry += __shfl(v, 63);
    }
    if (lane == 0) bbase[NB_BUCKETS] = carry;
}

__global__ __launch_bounds__(256) void kb_scatter(const int* __restrict__ src,
                                                  const int* __restrict__ dst,
                                                  int* __restrict__ bcount,
                                                  unsigned* __restrict__ arena) {
    __shared__ unsigned staged[CHUNK];            // 16 KB
    __shared__ unsigned short sbuck[CHUNK];       // 8 KB
    __shared__ int hist[NB_BUCKETS];
    __shared__ int lofs[NB_BUCKETS];
    __shared__ int lcur[NB_BUCKETS];
    __shared__ int gbase[NB_BUCKETS];
    int t = threadIdx.x;
    int lane = t & 63, wv = t >> 6;
    for (int i = t; i < NB_BUCKETS; i += 256) hist[i] = 0;
    __syncthreads();
    int chunk0 = blockIdx.x * CHUNK;
    int cN = min(CHUNK, N_EDGES - chunk0);
    for (int i = t; i < cN; i += 256) atomicAdd(&hist[dst[chunk0 + i] >> 8], 1);
    __syncthreads();
    if (wv == 0) {  // exclusive scan hist -> lofs
        int carry = 0;
        for (int c = 0; c < (NB_BUCKETS + 63) / 64; ++c) {
            int idx = c * 64 + lane;
            int v = (idx < NB_BUCKETS) ? hist[idx] : 0;
            int orig = v;
            for (int d = 1; d < 64; d <<= 1) {
                int u = __shfl_up(v, d);
                if (lane >= d) v += u;
            }
            if (idx < NB_BUCKETS) lofs[idx] = v - orig + carry;
            carry += __shfl(v, 63);
        }
    }
    __syncthreads();
    for (int i = t; i < NB_BUCKETS; i += 256) {
        lcur[i] = lofs[i];
        gbase[i] = hist[i] ? (atomicAdd(&bcount[i], hist[i]) + i * ARENA_CAP) : 0;
    }
    __syncthreads();
    for (int i = t; i < cN; i += 256) {  // stage bucket-major in LDS
        int e = chunk0 + i;
        int d = dst[e];
        int b = d >> 8;
        int lp = atomicAdd(&lcur[b], 1);
        staged[lp] = ((unsigned)src[e] << 8) | (unsigned)(d & 255);
        sbuck[lp] = (unsigned short)b;
    }
    __syncthreads();
    for (int p = t; p < cN; p += 256) {  // coalesced copy-out
        int b = sbuck[p];
        arena[gbase[b] + (p - lofs[b])] = staged[p];
    }
}

__global__ __launch_bounds__(256) void k_bfin(const unsigned* __restrict__ arena,
                                              const int* __restrict__ bbase,
                                              int* __restrict__ ssrc,
                                              int* __restrict__ off,
                                              float* __restrict__ dis) {
    __shared__ int cnt[256];
    __shared__ int lofs[256];
    __shared__ int lcur[256];
    int t = threadIdx.x;
    int lane = t & 63, wv = t >> 6;
    cnt[t] = 0;
    __syncthreads();
    int b = blockIdx.x;
    int lo = bbase[b];
    int cntB = bbase[b + 1] - lo;
    const unsigned* ap = arena + (size_t)b * ARENA_CAP;
    for (int e = t; e < cntB; e += 256) atomicAdd(&cnt[ap[e] & 255], 1);
    __syncthreads();
    if (wv == 0) {
        int carry = 0;
#pragma unroll
        for (int c = 0; c < 4; ++c) {
            int idx = c * 64 + lane;
            int v = cnt[idx];
            int orig = v;
            for (int d = 1; d < 64; d <<= 1) {
                int u = __shfl_up(v, d);
                if (lane >= d) v += u;
            }
            lofs[idx] = v - orig + carry;
            carry += __shfl(v, 63);
        }
    }
    __syncthreads();
    lcur[t] = lofs[t];
    int node = b * 256 + t;
    if (node < N_NODES) {
        off[node] = lo + lofs[t];
        dis[node] = rsqrtf((float)cnt[t] + 1.0f);  // +1 = self-loop
    }
    if (b == NB_BUCKETS - 1 && t == 0) off[N_NODES] = N_EDGES;
    __syncthreads();
    for (int e = t; e < cntB; e += 256) {
        unsigned pk = ap[e];
        int p = atomicAdd(&lcur[pk & 255u], 1);
        ssrc[lo + p] = (int)(pk >> 8);
    }
}

// ---------------- weight transpose + bf16 cast (once per launch) -----------

__global__ __launch_bounds__(256) void k_wprep(const float* __restrict__ W1,
                                               const float* __restrict__ W2,
                                               const float* __restrict__ W3,
                                               unsigned short* __restrict__ Wt1,
                                               unsigned short* __restrict__ Wt2,
                                               unsigned short* __restrict__ Wt3) {
    int t = blockIdx.x * 256 + threadIdx.x;
    if (t < 64 * 128) {  // Wt1[n][k] = bf16(W1[k][n]), n<64, k<128
        int n = t >> 7, k = t & 127;
        Wt1[t] = (unsigned short)f2bf_rne(W1[k * 64 + n]);
    }
    if (t < 64 * 64) {   // Wt2/Wt3[n][k], n<64, k<64
        int n = t >> 6, k = t & 63;
        Wt2[t] = (unsigned short)f2bf_rne(W2[k * 64 + n]);
        Wt3[t] = (unsigned short)f2bf_rne(W3[k * 64 + n]);
    }
}

// ---------------- conv GEMM: MFMA bf16, g16 = bf16(dis * A@W) ---------------
// block = 256 thr / 4 waves; tile 64 rows x 64 cols; mfma_f32_16x16x32_bf16.
template <int K, bool AF32>
__global__ __launch_bounds__(256) void k_gemm(const void* __restrict__ Ain,
                                              const unsigned short* __restrict__ Wt,
                                              const float* __restrict__ dis,
                                              unsigned* __restrict__ g16) {
    constexpr int PITCH = K + 8;  // shorts; keeps rows 16B-aligned
    constexpr int ABYTES = 2 * 64 * PITCH * 2;
    constexpr int CBYTES = 64 * 68 * 4;
    constexpr int SMEM = ABYTES > CBYTES ? ABYTES : CBYTES;
    __shared__ __align__(16) char smem[SMEM];
    short* As = (short*)smem;
    short* Bs = As + 64 * PITCH;
    float* Cs = (float*)smem;   // overlays As/Bs after MFMA phase
    constexpr int CP = 68;

    int t = threadIdx.x, lane = t & 63, w = t >> 6;
    int row0 = blockIdx.x * 64;

    constexpr int UN = 64 * (K / 8);  // 16B units per 64xK tile
#pragma unroll
    for (int u = t; u < UN; u += 256) {  // stage A (cast f32->bf16 if needed)
        int r = u / (K / 8), c = u % (K / 8);
        int grow = row0 + r;
        grow = grow < N_NODES ? grow : N_NODES - 1;
        uint4 o;
        if (AF32) {
            const float* Ap = (const float*)Ain + (size_t)grow * K + c * 8;
            float4 f0 = *(const float4*)Ap;
            float4 f1 = *(const float4*)(Ap + 4);
            o.x = pack2(f0.x, f0.y); o.y = pack2(f0.z, f0.w);
            o.z = pack2(f1.x, f1.y); o.w = pack2(f1.z, f1.w);
        } else {
            o = ((const uint4*)Ain)[(size_t)grow * (K / 8) + c];
        }
        *(uint4*)&As[r * PITCH + c * 8] = o;
    }
#pragma unroll
    for (int u = t; u < UN; u += 256) {  // stage B = Wt (already bf16, [n][K])
        int n = u / (K / 8), c = u % (K / 8);
        *(uint4*)&Bs[n * PITCH + c * 8] = *(const uint4*)&Wt[n * K + c * 8];
    }
    __syncthreads();

    using frag = __attribute__((ext_vector_type(8))) short;
    using fragc = __attribute__((ext_vector_type(4))) float;
    fragc z = {0.f, 0.f, 0.f, 0.f};
    fragc acc[4] = {z, z, z, z};
    int m = lane & 15, quad = lane >> 4;
#pragma unroll
    for (int ks = 0; ks < K / 32; ++ks) {
        frag a = *(frag*)&As[(w * 16 + m) * PITCH + ks * 32 + quad * 8];
#pragma unroll
        for (int nt = 0; nt < 4; ++nt) {
            frag b = *(frag*)&Bs[(nt * 16 + m) * PITCH + ks * 32 + quad * 8];
            acc[nt] = __builtin_amdgcn_mfma_f32_16x16x32_bf16(a, b, acc[nt], 0, 0, 0);
        }
    }
    __syncthreads();  // done reading As/Bs; reuse as Cs
#pragma unroll
    for (int nt = 0; nt < 4; ++nt)
#pragma unroll
        for (int reg = 0; reg < 4; ++reg)
            Cs[(w * 16 + quad * 4 + reg) * CP + nt * 16 + m] = acc[nt][reg];
    __syncthreads();

    {   // epilogue: thread -> (row, 16-col segment); scale by dis, pack bf16
        int r = t >> 2, c0 = (t & 3) * 16;
        int grow = row0 + r;
        if (grow < N_NODES) {
            float dr = dis[grow];
            const float* cp = &Cs[r * CP + c0];
            uint4 o0, o1;
            o0.x = pack2(cp[0] * dr, cp[1] * dr);
            o0.y = pack2(cp[2] * dr, cp[3] * dr);
            o0.z = pack2(cp[4] * dr, cp[5] * dr);
            o0.w = pack2(cp[6] * dr, cp[7] * dr);
            o1.x = pack2(cp[8] * dr, cp[9] * dr);
            o1.y = pack2(cp[10] * dr, cp[11] * dr);
            o1.z = pack2(cp[12] * dr, cp[13] * dr);
            o1.w = pack2(cp[14] * dr, cp[15] * dr);
            ((uint4*)g16)[(size_t)grow * 8 + (c0 >> 3)] = o0;
            ((uint4*)g16)[(size_t)grow * 8 + (c0 >> 3) + 1] = o1;
        }
    }
}

// ---------------- aggregate: row-per-8-lanes, no cross-lane reduction -------
// Wave = 8 rows; lanes li in [0,8) of a row-group own the li-th uint4 (16B)
// of the row and accumulate over all the row's edges. Unroll-2 keeps 16
// row-gathers in flight per wave. h16 = bf16(act(dis*(self+sum)+b)).
template <bool RELU>
__global__ __launch_bounds__(256) void k_aggr(const unsigned* __restrict__ g16,
                                              const int* __restrict__ off,
                                              const int* __restrict__ ssrc,
                                              const float* __restrict__ dis,
                                              const float* __restrict__ bias,
                                              unsigned* __restrict__ h16) {
    int lane = threadIdx.x & 63, wv = threadIdx.x >> 6;
    int r8 = lane >> 3;    // row sub-index 0..7 within wave
    int li = lane & 7;     // 16B segment of the 128B row
    int row = blockIdx.x * 32 + wv * 8 + r8;
    if (row >= N_NODES) return;
    const uint4* g4 = (const uint4*)g16;   // row = 8 uint4
    float2 acc[4] = {make_float2(0.f, 0.f), make_float2(0.f, 0.f),
                     make_float2(0.f, 0.f), make_float2(0.f, 0.f)};
    int lo = off[row], hi = off[row + 1];
    int e = lo;
    for (; e + 1 < hi; e += 2) {  // two edges in flight per row
        unsigned o0 = (unsigned)ssrc[e] * 8u + (unsigned)li;
        unsigned o1 = (unsigned)ssrc[e + 1] * 8u + (unsigned)li;
        uint4 v0 = g4[o0];
        uint4 v1 = g4[o1];
        acc2(acc[0], bf_pair(v0.x)); acc2(acc[0], bf_pair(v1.x));
        acc2(acc[1], bf_pair(v0.y)); acc2(acc[1], bf_pair(v1.y));
        acc2(acc[2], bf_pair(v0.z)); acc2(acc[2], bf_pair(v1.z));
        acc2(acc[3], bf_pair(v0.w)); acc2(acc[3], bf_pair(v1.w));
    }
    if (e < hi) {
        unsigned o = (unsigned)ssrc[e] * 8u + (unsigned)li;
        uint4 v = g4[o];
        acc2(acc[0], bf_pair(v.x));
        acc2(acc[1], bf_pair(v.y));
        acc2(acc[2], bf_pair(v.z));
        acc2(acc[3], bf_pair(v.w));
    }
    // epilogue: self + bias + scale, pack, store (each lane owns its 16B)
    unsigned base = (unsigned)row * 8u + (unsigned)li;
    uint4 sv = g4[base];
    float2 sp[4] = {bf_pair(sv.x), bf_pair(sv.y), bf_pair(sv.z), bf_pair(sv.w)};
    float dr = dis[row];
    float4 b0 = ((const float4*)bias)[li * 2];
    float4 b1 = ((const float4*)bias)[li * 2 + 1];
    float bb[8] = {b0.x, b0.y, b0.z, b0.w, b1.x, b1.y, b1.z, b1.w};
    float o[8];
#pragma unroll
    for (int j = 0; j < 4; ++j) {
        o[2 * j]     = dr * (acc[j].x + sp[j].x) + bb[2 * j];
        o[2 * j + 1] = dr * (acc[j].y + sp[j].y) + bb[2 * j + 1];
    }
    if (RELU) {
#pragma unroll
        for (int j = 0; j < 8; ++j) o[j] = fmaxf(o[j], 0.f);
    }
    uint4 wvo;
    wvo.x = pack2(o[0], o[1]);
    wvo.y = pack2(o[2], o[3]);
    wvo.z = pack2(o[4], o[5]);
    wvo.w = pack2(o[6], o[7]);
    ((uint4*)h16)[base] = wvo;
}

// ---------------- pooling + classifier ----------------

__global__ __launch_bounds__(256) void k_pool1(const unsigned short* __restrict__ h16,
                                               const int* __restrict__ batch,
                                               float* __restrict__ sums) {
    int lane = threadIdx.x & 63, wv = threadIdx.x >> 6;
    int node0 = blockIdx.x * 256 + wv * 64;
    int node1 = min(node0 + 64, N_NODES);
    float acc = 0.f;
    int cur = -1;
    for (int i = node0; i < node1; ++i) {
        int bi = batch[i];
        if (bi != cur) {
            if (cur >= 0) atomicAdd(&sums[cur * HID + lane], acc);
            acc = 0.f;
            cur = bi;
        }
        unsigned u = h16[(size_t)i * HID + lane];
        acc += __uint_as_float(u << 16);
    }
    if (cur >= 0) atomicAdd(&sums[cur * HID + lane], acc);
}

__device__ inline int lower_bound_batch(const int* batch, int key) {
    int lo = 0, hi = N_NODES;
    while (lo < hi) {
        int mid = (lo + hi) >> 1;
        if (batch[mid] < key) lo = mid + 1;
        else hi = mid;
    }
    return lo;
}

__global__ __launch_bounds__(256) void k_cls(const float* __restrict__ sums,
                                             const int* __restrict__ batch,
                                             const float* __restrict__ Wc1,
                                             const float* __restrict__ bc1,
                                             const float* __restrict__ Wc2,
                                             const float* __restrict__ bc2,
                                             float* __restrict__ out) {
    __shared__ float pooled[N_GRAPHS][HID];
    __shared__ float hc[N_GRAPHS][HID / 2];
    __shared__ float cnts[N_GRAPHS];
    int t = threadIdx.x;
    if (t < N_GRAPHS) {
        int lo = lower_bound_batch(batch, t);
        int hi = lower_bound_batch(batch, t + 1);
        cnts[t] = fmaxf((float)(hi - lo), 1.0f);
    }
    __syncthreads();
    for (int idx = t; idx < N_GRAPHS * HID; idx += 256) {
        int gi = idx >> 6;
        pooled[gi][idx & 63] = sums[idx] / cnts[gi];
    }
    __syncthreads();
    for (int idx = t; idx < N_GRAPHS * (HID / 2); idx += 256) {
        int gi = idx >> 5, f = idx & 31;
        float a = bc1[f];
#pragma unroll
        for (int k = 0; k < HID; ++k) a = fmaf(pooled[gi][k], Wc1[k * (HID / 2) + f], a);
        hc[gi][f] = fmaxf(a, 0.f);
    }
    __syncthreads();
    for (int idx = t; idx < N_GRAPHS * OUT_DIM; idx += 256) {
        int gi = idx >> 1, f = idx & 1;
        float a = bc2[f];
#pragma unroll
        for (int k = 0; k < HID / 2; ++k) a = fmaf(hc[gi][k], Wc2[k * OUT_DIM + f], a);
        out[gi * OUT_DIM + f] = a;
    }
}

// ---------------- launch ----------------

extern "C" void kernel_launch(void* const* d_in, const int* in_sizes, int n_in,
                              void* d_out, int out_size, void* d_ws, size_t ws_size,
                              hipStream_t stream) {
    const float* x    = (const float*)d_in[0];
    const int*   eidx = (const int*)d_in[1];
    const int*   batch= (const int*)d_in[2];
    const float* W1 = (const float*)d_in[3];  const float* b1 = (const float*)d_in[4];
    const float* W2 = (const float*)d_in[5];  const float* b2 = (const float*)d_in[6];
    const float* W3 = (const float*)d_in[7];  const float* b3 = (const float*)d_in[8];
    const float* Wc1 = (const float*)d_in[9];  const float* bc1 = (const float*)d_in[10];
    const float* Wc2 = (const float*)d_in[11]; const float* bc2 = (const float*)d_in[12];
    float* out = (float*)d_out;

    const int* esrc = eidx;
    const int* edst = eidx + N_EDGES;

    size_t o = 0;
    auto alloc = [&](size_t bytes) {
        void* p = (char*)d_ws + o;
        o += (bytes + 255) & ~(size_t)255;
        return p;
    };
    int*            bcount = (int*)alloc((size_t)NB_BUCKETS * 4);
    int*            bbase  = (int*)alloc((size_t)(NB_BUCKETS + 1) * 4);
    float*          dis    = (float*)alloc((size_t)N_NODES * 4);
    unsigned*       arena  = (unsigned*)alloc((size_t)NB_BUCKETS * ARENA_CAP * 4);
    int*            ssrc   = (int*)alloc((size_t)N_EDGES * 4);
    int*            off    = (int*)alloc((size_t)(N_NODES + 1) * 4);
    unsigned*       g16    = (unsigned*)alloc((size_t)N_NODES * HID * 2);
    unsigned*       h16    = (unsigned*)alloc((size_t)N_NODES * HID * 2);
    unsigned short* Wt1    = (unsigned short*)alloc((size_t)64 * 128 * 2);
    unsigned short* Wt2    = (unsigned short*)alloc((size_t)64 * 64 * 2);
    unsigned short* Wt3    = (unsigned short*)alloc((size_t)64 * 64 * 2);
    float*          sums   = (float*)alloc((size_t)N_GRAPHS * HID * 4);
    (void)ws_size;

    const int TB = 256;
    int gridG = (N_NODES + 63) / 64;
    int gridR = (N_NODES + 31) / 32;   // aggr: 32 rows per block (8 per wave)

    // 1) preprocessing: arena bucketing -> CSR; weight transpose/cast
    hipMemsetAsync(bcount, 0, (size_t)NB_BUCKETS * 4, stream);
    hipMemsetAsync(sums, 0, (size_t)N_GRAPHS * HID * 4, stream);
    k_wprep<<<32, TB, 0, stream>>>(W1, W2, W3, Wt1, Wt2, Wt3);
    kb_scatter<<<NCHUNKS, TB, 0, stream>>>(esrc, edst, bcount, arena);
    kb_scan<<<1, 64, 0, stream>>>(bcount, bbase);
    k_bfin<<<NB_BUCKETS, TB, 0, stream>>>(arena, bbase, ssrc, off, dis);

    // 2) conv1 (A = x f32, cast in staging)
    k_gemm<IN_DIM, true><<<gridG, TB, 0, stream>>>(x, Wt1, dis, g16);
    k_aggr<true><<<gridR, TB, 0, stream>>>(g16, off, ssrc, dis, b1, h16);

    // 3) conv2 (A = h16 bf16)
    k_gemm<HID, false><<<gridG, TB, 0, stream>>>(h16, Wt2, dis, g16);
    k_aggr<true><<<gridR, TB, 0, stream>>>(g16, off, ssrc, dis, b2, h16);

    // 4) conv3 (no relu)
    k_gemm<HID, false><<<gridG, TB, 0, stream>>>(h16, Wt3, dis, g16);
    k_aggr<false><<<gridR, TB, 0, stream>>>(g16, off, ssrc, dis, b3, h16);

    // 5) pool + classifier
    k_pool1<<<NB_BUCKETS, TB, 0, stream>>>((const unsigned short*)h16, batch, sums);
    k_cls<<<1, TB, 0, stream>>>(sums, batch, Wc1, bc1, Wc2, bc2, out);
}

// Round 12
// 320.718 us; speedup vs baseline: 1.3753x; 1.0388x over previous
//
#include <hip/hip_runtime.h>
#include <hip/hip_bf16.h>

#define N_NODES 100000
#define N_EDGES 1600000
#define IN_DIM 128
#define HID 64
#define N_GRAPHS 64
#define OUT_DIM 2

#define NB_BUCKETS ((N_NODES + 255) / 256)   // 391 buckets of 256 nodes
#define CHUNK 4096
#define NCHUNKS ((N_EDGES + CHUNK - 1) / CHUNK)  // 391
#define ARENA_CAP 6144   // per-bucket arena slots; mean 4092, sigma 64 -> +32 sigma

// ---------------- bf16 pack/unpack (RNE) ----------------

__device__ inline unsigned f2bf_rne(float f) {
    unsigned u = __float_as_uint(f);
    u += 0x7FFFu + ((u >> 16) & 1u);
    return u >> 16;
}
__device__ inline unsigned pack2(float lo, float hi) {
    return f2bf_rne(lo) | (f2bf_rne(hi) << 16);
}
__device__ inline float bf_lo(unsigned w) { return __uint_as_float(w << 16); }
__device__ inline float bf_hi(unsigned w) { return __uint_as_float(w & 0xFFFF0000u); }
__device__ inline float2 bf_pair(unsigned w) {
    return make_float2(bf_lo(w), bf_hi(w));
}
__device__ inline void acc2(float2& a, float2 b) { a.x += b.x; a.y += b.y; }
__device__ inline void accv(float2 a[4], uint4 v) {
    acc2(a[0], bf_pair(v.x)); acc2(a[1], bf_pair(v.y));
    acc2(a[2], bf_pair(v.z)); acc2(a[3], bf_pair(v.w));
}

// ---------------- edge bucketing (single-pass arena scatter) ----------------

__global__ void kb_scan(const int* __restrict__ bcount, int* __restrict__ bbase) {
    int lane = threadIdx.x;
    int carry = 0;
    for (int c = 0; c < (NB_BUCKETS + 63) / 64; ++c) {
        int idx = c * 64 + lane;
        int v = (idx < NB_BUCKETS) ? bcount[idx] : 0;
        int orig = v;
        for (int d = 1; d < 64; d <<= 1) {
            int u = __shfl_up(v, d);
            if (lane >= d) v += u;
        }
        if (idx < NB_BUCKETS) bbase[idx] = v - orig + carry;
        carry += __shfl(v, 63);
    }
    if (lane == 0) bbase[NB_BUCKETS] = carry;
}

__global__ __launch_bounds__(256) void kb_scatter(const int* __restrict__ src,
                                                  const int* __restrict__ dst,
                                                  int* __restrict__ bcount,
                                                  unsigned* __restrict__ arena) {
    __shared__ unsigned staged[CHUNK];            // 16 KB
    __shared__ unsigned short sbuck[CHUNK];       // 8 KB
    __shared__ int hist[NB_BUCKETS];
    __shared__ int lofs[NB_BUCKETS];
    __shared__ int lcur[NB_BUCKETS];
    __shared__ int gbase[NB_BUCKETS];
    int t = threadIdx.x;
    int lane = t & 63, wv = t >> 6;
    for (int i = t; i < NB_BUCKETS; i += 256) hist[i] = 0;
    __syncthreads();
    int chunk0 = blockIdx.x * CHUNK;
    int cN = min(CHUNK, N_EDGES - chunk0);
    for (int i = t; i < cN; i += 256) atomicAdd(&hist[dst[chunk0 + i] >> 8], 1);
    __syncthreads();
    if (wv == 0) {  // exclusive scan hist -> lofs
        int carry = 0;
        for (int c = 0; c < (NB_BUCKETS + 63) / 64; ++c) {
            int idx = c * 64 + lane;
            int v = (idx < NB_BUCKETS) ? hist[idx] : 0;
            int orig = v;
            for (int d = 1; d < 64; d <<= 1) {
                int u = __shfl_up(v, d);
                if (lane >= d) v += u;
            }
            if (idx < NB_BUCKETS) lofs[idx] = v - orig + carry;
            carry += __shfl(v, 63);
        }
    }
    __syncthreads();
    for (int i = t; i < NB_BUCKETS; i += 256) {
        lcur[i] = lofs[i];
        gbase[i] = hist[i] ? (atomicAdd(&bcount[i], hist[i]) + i * ARENA_CAP) : 0;
    }
    __syncthreads();
    for (int i = t; i < cN; i += 256) {  // stage bucket-major in LDS
        int e = chunk0 + i;
        int d = dst[e];
        int b = d >> 8;
        int lp = atomicAdd(&lcur[b], 1);
        staged[lp] = ((unsigned)src[e] << 8) | (unsigned)(d & 255);
        sbuck[lp] = (unsigned short)b;
    }
    __syncthreads();
    for (int p = t; p < cN; p += 256) {  // coalesced copy-out
        int b = sbuck[p];
        arena[gbase[b] + (p - lofs[b])] = staged[p];
    }
}

__global__ __launch_bounds__(256) void k_bfin(const unsigned* __restrict__ arena,
                                              const int* __restrict__ bbase,
                                              int* __restrict__ ssrc,
                                              int* __restrict__ off,
                                              float* __restrict__ dis) {
    __shared__ int cnt[256];
    __shared__ int lofs[256];
    __shared__ int lcur[256];
    int t = threadIdx.x;
    int lane = t & 63, wv = t >> 6;
    cnt[t] = 0;
    __syncthreads();
    int b = blockIdx.x;
    int lo = bbase[b];
    int cntB = bbase[b + 1] - lo;
    const unsigned* ap = arena + (size_t)b * ARENA_CAP;
    for (int e = t; e < cntB; e += 256) atomicAdd(&cnt[ap[e] & 255], 1);
    __syncthreads();
    if (wv == 0) {
        int carry = 0;
#pragma unroll
        for (int c = 0; c < 4; ++c) {
            int idx = c * 64 + lane;
            int v = cnt[idx];
            int orig = v;
            for (int d = 1; d < 64; d <<= 1) {
                int u = __shfl_up(v, d);
                if (lane >= d) v += u;
            }
            lofs[idx] = v - orig + carry;
            carry += __shfl(v, 63);
        }
    }
    __syncthreads();
    lcur[t] = lofs[t];
    int node = b * 256 + t;
    if (node < N_NODES) {
        off[node] = lo + lofs[t];
        dis[node] = rsqrtf((float)cnt[t] + 1.0f);  // +1 = self-loop
    }
    if (b == NB_BUCKETS - 1 && t == 0) off[N_NODES] = N_EDGES;
    __syncthreads();
    for (int e = t; e < cntB; e += 256) {
        unsigned pk = ap[e];
        int p = atomicAdd(&lcur[pk & 255u], 1);
        ssrc[lo + p] = (int)(pk >> 8);
    }
}

// ---------------- weight transpose + bf16 cast (once per launch) -----------

__global__ __launch_bounds__(256) void k_wprep(const float* __restrict__ W1,
                                               const float* __restrict__ W2,
                                               const float* __restrict__ W3,
                                               unsigned short* __restrict__ Wt1,
                                               unsigned short* __restrict__ Wt2,
                                               unsigned short* __restrict__ Wt3) {
    int t = blockIdx.x * 256 + threadIdx.x;
    if (t < 64 * 128) {  // Wt1[n][k] = bf16(W1[k][n]), n<64, k<128
        int n = t >> 7, k = t & 127;
        Wt1[t] = (unsigned short)f2bf_rne(W1[k * 64 + n]);
    }
    if (t < 64 * 64) {   // Wt2/Wt3[n][k], n<64, k<64
        int n = t >> 6, k = t & 63;
        Wt2[t] = (unsigned short)f2bf_rne(W2[k * 64 + n]);
        Wt3[t] = (unsigned short)f2bf_rne(W3[k * 64 + n]);
    }
}

// ---------------- conv1 GEMM: MFMA bf16, g16 = bf16(dis * A@W) --------------
// block = 256 thr / 4 waves; tile 64 rows x 64 cols; mfma_f32_16x16x32_bf16.
template <int K, bool AF32>
__global__ __launch_bounds__(256) void k_gemm(const void* __restrict__ Ain,
                                              const unsigned short* __restrict__ Wt,
                                              const float* __restrict__ dis,
                                              unsigned* __restrict__ g16) {
    constexpr int PITCH = K + 8;  // shorts; keeps rows 16B-aligned
    constexpr int ABYTES = 2 * 64 * PITCH * 2;
    constexpr int CBYTES = 64 * 68 * 4;
    constexpr int SMEM = ABYTES > CBYTES ? ABYTES : CBYTES;
    __shared__ __align__(16) char smem[SMEM];
    short* As = (short*)smem;
    short* Bs = As + 64 * PITCH;
    float* Cs = (float*)smem;   // overlays As/Bs after MFMA phase
    constexpr int CP = 68;

    int t = threadIdx.x, lane = t & 63, w = t >> 6;
    int row0 = blockIdx.x * 64;

    constexpr int UN = 64 * (K / 8);  // 16B units per 64xK tile
#pragma unroll
    for (int u = t; u < UN; u += 256) {  // stage A (cast f32->bf16 if needed)
        int r = u / (K / 8), c = u % (K / 8);
        int grow = row0 + r;
        grow = grow < N_NODES ? grow : N_NODES - 1;
        uint4 o;
        if (AF32) {
            const float* Ap = (const float*)Ain + (size_t)grow * K + c * 8;
            float4 f0 = *(const float4*)Ap;
            float4 f1 = *(const float4*)(Ap + 4);
            o.x = pack2(f0.x, f0.y); o.y = pack2(f0.z, f0.w);
            o.z = pack2(f1.x, f1.y); o.w = pack2(f1.z, f1.w);
        } else {
            o = ((const uint4*)Ain)[(size_t)grow * (K / 8) + c];
        }
        *(uint4*)&As[r * PITCH + c * 8] = o;
    }
#pragma unroll
    for (int u = t; u < UN; u += 256) {  // stage B = Wt (already bf16, [n][K])
        int n = u / (K / 8), c = u % (K / 8);
        *(uint4*)&Bs[n * PITCH + c * 8] = *(const uint4*)&Wt[n * K + c * 8];
    }
    __syncthreads();

    using frag = __attribute__((ext_vector_type(8))) short;
    using fragc = __attribute__((ext_vector_type(4))) float;
    fragc z = {0.f, 0.f, 0.f, 0.f};
    fragc acc[4] = {z, z, z, z};
    int m = lane & 15, quad = lane >> 4;
#pragma unroll
    for (int ks = 0; ks < K / 32; ++ks) {
        frag a = *(frag*)&As[(w * 16 + m) * PITCH + ks * 32 + quad * 8];
#pragma unroll
        for (int nt = 0; nt < 4; ++nt) {
            frag b = *(frag*)&Bs[(nt * 16 + m) * PITCH + ks * 32 + quad * 8];
            acc[nt] = __builtin_amdgcn_mfma_f32_16x16x32_bf16(a, b, acc[nt], 0, 0, 0);
        }
    }
    __syncthreads();  // done reading As/Bs; reuse as Cs
#pragma unroll
    for (int nt = 0; nt < 4; ++nt)
#pragma unroll
        for (int reg = 0; reg < 4; ++reg)
            Cs[(w * 16 + quad * 4 + reg) * CP + nt * 16 + m] = acc[nt][reg];
    __syncthreads();

    {   // epilogue: thread -> (row, 16-col segment); scale by dis, pack bf16
        int r = t >> 2, c0 = (t & 3) * 16;
        int grow = row0 + r;
        if (grow < N_NODES) {
            float dr = dis[grow];
            const float* cp = &Cs[r * CP + c0];
            uint4 o0, o1;
            o0.x = pack2(cp[0] * dr, cp[1] * dr);
            o0.y = pack2(cp[2] * dr, cp[3] * dr);
            o0.z = pack2(cp[4] * dr, cp[5] * dr);
            o0.w = pack2(cp[6] * dr, cp[7] * dr);
            o1.x = pack2(cp[8] * dr, cp[9] * dr);
            o1.y = pack2(cp[10] * dr, cp[11] * dr);
            o1.z = pack2(cp[12] * dr, cp[13] * dr);
            o1.w = pack2(cp[14] * dr, cp[15] * dr);
            ((uint4*)g16)[(size_t)grow * 8 + (c0 >> 3)] = o0;
            ((uint4*)g16)[(size_t)grow * 8 + (c0 >> 3) + 1] = o1;
        }
    }
}

// ---------------- fused aggr + next-conv GEMM -------------------------------
// Phase 1: aggregate 64 rows (gather gin) -> h = relu(dis*(self+sum)+b),
//          packed bf16 straight into the LDS A-tile (no h16 round-trip).
// Phase 2: MFMA gemm h @ Wt, epilogue gout = bf16(dis * .), double-buffered.
__global__ __launch_bounds__(256) void k_aggr_gemm(const unsigned* __restrict__ gin,
                                                   const int* __restrict__ off,
                                                   const int* __restrict__ ssrc,
                                                   const float* __restrict__ dis,
                                                   const float* __restrict__ bias,
                                                   const unsigned short* __restrict__ Wt,
                                                   unsigned* __restrict__ gout) {
    constexpr int K = HID;          // 64
    constexpr int PITCH = K + 8;    // 72 shorts
    constexpr int ABYTES = 2 * 64 * PITCH * 2;   // As + Bs
    constexpr int CBYTES = 64 * 68 * 4;
    constexpr int SMEM = ABYTES > CBYTES ? ABYTES : CBYTES;
    __shared__ __align__(16) char smem[SMEM];
    short* As = (short*)smem;
    short* Bs = As + 64 * PITCH;
    float* Cs = (float*)smem;
    constexpr int CP = 68;

    int t = threadIdx.x, lane = t & 63, w = t >> 6;
    int row0 = blockIdx.x * 64;
    int r8 = lane >> 3, li = lane & 7;
    const uint4* g4 = (const uint4*)gin;

    // stage B = Wt
#pragma unroll
    for (int u = t; u < 64 * 8; u += 256) {
        int n = u >> 3, c = u & 7;
        *(uint4*)&Bs[n * PITCH + c * 8] = *(const uint4*)&Wt[n * K + c * 8];
    }

    // phase 1: aggregate rows into As (each lane-group of 8 handles a row)
    float4 b0 = ((const float4*)bias)[li * 2];
    float4 b1 = ((const float4*)bias)[li * 2 + 1];
#pragma unroll
    for (int half = 0; half < 2; ++half) {
        int r = w * 8 + r8 + half * 32;
        int row = row0 + r;
        int crow = row < N_NODES ? row : N_NODES - 1;
        float2 acc[4] = {make_float2(0.f, 0.f), make_float2(0.f, 0.f),
                         make_float2(0.f, 0.f), make_float2(0.f, 0.f)};
        int lo = off[crow], hi = off[crow + 1];
        int e = lo;
        for (; e + 3 < hi; e += 4) {  // 4 row-gathers in flight
            unsigned o0 = (unsigned)ssrc[e] * 8u + (unsigned)li;
            unsigned o1 = (unsigned)ssrc[e + 1] * 8u + (unsigned)li;
            unsigned o2 = (unsigned)ssrc[e + 2] * 8u + (unsigned)li;
            unsigned o3 = (unsigned)ssrc[e + 3] * 8u + (unsigned)li;
            uint4 v0 = g4[o0], v1 = g4[o1], v2 = g4[o2], v3 = g4[o3];
            accv(acc, v0); accv(acc, v1); accv(acc, v2); accv(acc, v3);
        }
        for (; e < hi; ++e) {
            uint4 v = g4[(unsigned)ssrc[e] * 8u + (unsigned)li];
            accv(acc, v);
        }
        uint4 sv = g4[(unsigned)crow * 8u + (unsigned)li];
        float2 sp[4] = {bf_pair(sv.x), bf_pair(sv.y), bf_pair(sv.z), bf_pair(sv.w)};
        float dr = dis[crow];
        float bb[8] = {b0.x, b0.y, b0.z, b0.w, b1.x, b1.y, b1.z, b1.w};
        float o[8];
#pragma unroll
        for (int j = 0; j < 4; ++j) {
            o[2 * j]     = fmaxf(dr * (acc[j].x + sp[j].x) + bb[2 * j], 0.f);
            o[2 * j + 1] = fmaxf(dr * (acc[j].y + sp[j].y) + bb[2 * j + 1], 0.f);
        }
        uint4 hv;
        hv.x = pack2(o[0], o[1]);
        hv.y = pack2(o[2], o[3]);
        hv.z = pack2(o[4], o[5]);
        hv.w = pack2(o[6], o[7]);
        *(uint4*)&As[r * PITCH + li * 8] = hv;
    }
    __syncthreads();

    // phase 2: MFMA gemm
    using frag = __attribute__((ext_vector_type(8))) short;
    using fragc = __attribute__((ext_vector_type(4))) float;
    fragc z = {0.f, 0.f, 0.f, 0.f};
    fragc acc[4] = {z, z, z, z};
    int m = lane & 15, quad = lane >> 4;
#pragma unroll
    for (int ks = 0; ks < K / 32; ++ks) {
        frag a = *(frag*)&As[(w * 16 + m) * PITCH + ks * 32 + quad * 8];
#pragma unroll
        for (int nt = 0; nt < 4; ++nt) {
            frag b = *(frag*)&Bs[(nt * 16 + m) * PITCH + ks * 32 + quad * 8];
            acc[nt] = __builtin_amdgcn_mfma_f32_16x16x32_bf16(a, b, acc[nt], 0, 0, 0);
        }
    }
    __syncthreads();
#pragma unroll
    for (int nt = 0; nt < 4; ++nt)
#pragma unroll
        for (int reg = 0; reg < 4; ++reg)
            Cs[(w * 16 + quad * 4 + reg) * CP + nt * 16 + m] = acc[nt][reg];
    __syncthreads();
    {
        int r = t >> 2, c0 = (t & 3) * 16;
        int grow = row0 + r;
        if (grow < N_NODES) {
            float dr = dis[grow];
            const float* cp = &Cs[r * CP + c0];
            uint4 o0, o1;
            o0.x = pack2(cp[0] * dr, cp[1] * dr);
            o0.y = pack2(cp[2] * dr, cp[3] * dr);
            o0.z = pack2(cp[4] * dr, cp[5] * dr);
            o0.w = pack2(cp[6] * dr, cp[7] * dr);
            o1.x = pack2(cp[8] * dr, cp[9] * dr);
            o1.y = pack2(cp[10] * dr, cp[11] * dr);
            o1.z = pack2(cp[12] * dr, cp[13] * dr);
            o1.w = pack2(cp[14] * dr, cp[15] * dr);
            ((uint4*)gout)[(size_t)grow * 8 + (c0 >> 3)] = o0;
            ((uint4*)gout)[(size_t)grow * 8 + (c0 >> 3) + 1] = o1;
        }
    }
}

// ---------------- final aggregate (conv3, no relu), bf16 out ----------------
template <bool RELU>
__global__ __launch_bounds__(256) void k_aggr(const unsigned* __restrict__ g16,
                                              const int* __restrict__ off,
                                              const int* __restrict__ ssrc,
                                              const float* __restrict__ dis,
                                              const float* __restrict__ bias,
                                              unsigned* __restrict__ h16) {
    int lane = threadIdx.x & 63, wv = threadIdx.x >> 6;
    int r8 = lane >> 3;
    int li = lane & 7;
    int row = blockIdx.x * 32 + wv * 8 + r8;
    if (row >= N_NODES) return;
    const uint4* g4 = (const uint4*)g16;
    float2 acc[4] = {make_float2(0.f, 0.f), make_float2(0.f, 0.f),
                     make_float2(0.f, 0.f), make_float2(0.f, 0.f)};
    int lo = off[row], hi = off[row + 1];
    int e = lo;
    for (; e + 3 < hi; e += 4) {
        unsigned o0 = (unsigned)ssrc[e] * 8u + (unsigned)li;
        unsigned o1 = (unsigned)ssrc[e + 1] * 8u + (unsigned)li;
        unsigned o2 = (unsigned)ssrc[e + 2] * 8u + (unsigned)li;
        unsigned o3 = (unsigned)ssrc[e + 3] * 8u + (unsigned)li;
        uint4 v0 = g4[o0], v1 = g4[o1], v2 = g4[o2], v3 = g4[o3];
        accv(acc, v0); accv(acc, v1); accv(acc, v2); accv(acc, v3);
    }
    for (; e < hi; ++e) {
        uint4 v = g4[(unsigned)ssrc[e] * 8u + (unsigned)li];
        accv(acc, v);
    }
    unsigned base = (unsigned)row * 8u + (unsigned)li;
    uint4 sv = g4[base];
    float2 sp[4] = {bf_pair(sv.x), bf_pair(sv.y), bf_pair(sv.z), bf_pair(sv.w)};
    float dr = dis[row];
    float4 b0 = ((const float4*)bias)[li * 2];
    float4 b1 = ((const float4*)bias)[li * 2 + 1];
    float bb[8] = {b0.x, b0.y, b0.z, b0.w, b1.x, b1.y, b1.z, b1.w};
    float o[8];
#pragma unroll
    for (int j = 0; j < 4; ++j) {
        o[2 * j]     = dr * (acc[j].x + sp[j].x) + bb[2 * j];
        o[2 * j + 1] = dr * (acc[j].y + sp[j].y) + bb[2 * j + 1];
    }
    if (RELU) {
#pragma unroll
        for (int j = 0; j < 8; ++j) o[j] = fmaxf(o[j], 0.f);
    }
    uint4 wvo;
    wvo.x = pack2(o[0], o[1]);
    wvo.y = pack2(o[2], o[3]);
    wvo.z = pack2(o[4], o[5]);
    wvo.w = pack2(o[6], o[7]);
    ((uint4*)h16)[base] = wvo;
}

// ---------------- pooling + classifier ----------------

__global__ __launch_bounds__(256) void k_pool1(const unsigned short* __restrict__ h16,
                                               const int* __restrict__ batch,
                                               float* __restrict__ sums) {
    int lane = threadIdx.x & 63, wv = threadIdx.x >> 6;
    int node0 = blockIdx.x * 256 + wv * 64;
    int node1 = min(node0 + 64, N_NODES);
    float acc = 0.f;
    int cur = -1;
    for (int i = node0; i < node1; ++i) {
        int bi = batch[i];
        if (bi != cur) {
            if (cur >= 0) atomicAdd(&sums[cur * HID + lane], acc);
            acc = 0.f;
            cur = bi;
        }
        unsigned u = h16[(size_t)i * HID + lane];
        acc += __uint_as_float(u << 16);
    }
    if (cur >= 0) atomicAdd(&sums[cur * HID + lane], acc);
}

__device__ inline int lower_bound_batch(const int* batch, int key) {
    int lo = 0, hi = N_NODES;
    while (lo < hi) {
        int mid = (lo + hi) >> 1;
        if (batch[mid] < key) lo = mid + 1;
        else hi = mid;
    }
    return lo;
}

__global__ __launch_bounds__(256) void k_cls(const float* __restrict__ sums,
                                             const int* __restrict__ batch,
                                             const float* __restrict__ Wc1,
                                             const float* __restrict__ bc1,
                                             const float* __restrict__ Wc2,
                                             const float* __restrict__ bc2,
                                             float* __restrict__ out) {
    __shared__ float pooled[N_GRAPHS][HID];
    __shared__ float hc[N_GRAPHS][HID / 2];
    __shared__ float cnts[N_GRAPHS];
    int t = threadIdx.x;
    if (t < N_GRAPHS) {
        int lo = lower_bound_batch(batch, t);
        int hi = lower_bound_batch(batch, t + 1);
        cnts[t] = fmaxf((float)(hi - lo), 1.0f);
    }
    __syncthreads();
    for (int idx = t; idx < N_GRAPHS * HID; idx += 256) {
        int gi = idx >> 6;
        pooled[gi][idx & 63] = sums[idx] / cnts[gi];
    }
    __syncthreads();
    for (int idx = t; idx < N_GRAPHS * (HID / 2); idx += 256) {
        int gi = idx >> 5, f = idx & 31;
        float a = bc1[f];
#pragma unroll
        for (int k = 0; k < HID; ++k) a = fmaf(pooled[gi][k], Wc1[k * (HID / 2) + f], a);
        hc[gi][f] = fmaxf(a, 0.f);
    }
    __syncthreads();
    for (int idx = t; idx < N_GRAPHS * OUT_DIM; idx += 256) {
        int gi = idx >> 1, f = idx & 1;
        float a = bc2[f];
#pragma unroll
        for (int k = 0; k < HID / 2; ++k) a = fmaf(hc[gi][k], Wc2[k * OUT_DIM + f], a);
        out[gi * OUT_DIM + f] = a;
    }
}

// ---------------- launch ----------------

extern "C" void kernel_launch(void* const* d_in, const int* in_sizes, int n_in,
                              void* d_out, int out_size, void* d_ws, size_t ws_size,
                              hipStream_t stream) {
    const float* x    = (const float*)d_in[0];
    const int*   eidx = (const int*)d_in[1];
    const int*   batch= (const int*)d_in[2];
    const float* W1 = (const float*)d_in[3];  const float* b1 = (const float*)d_in[4];
    const float* W2 = (const float*)d_in[5];  const float* b2 = (const float*)d_in[6];
    const float* W3 = (const float*)d_in[7];  const float* b3 = (const float*)d_in[8];
    const float* Wc1 = (const float*)d_in[9];  const float* bc1 = (const float*)d_in[10];
    const float* Wc2 = (const float*)d_in[11]; const float* bc2 = (const float*)d_in[12];
    float* out = (float*)d_out;

    const int* esrc = eidx;
    const int* edst = eidx + N_EDGES;

    size_t o = 0;
    auto alloc = [&](size_t bytes) {
        void* p = (char*)d_ws + o;
        o += (bytes + 255) & ~(size_t)255;
        return p;
    };
    int*            bcount = (int*)alloc((size_t)NB_BUCKETS * 4);
    int*            bbase  = (int*)alloc((size_t)(NB_BUCKETS + 1) * 4);
    float*          dis    = (float*)alloc((size_t)N_NODES * 4);
    unsigned*       arena  = (unsigned*)alloc((size_t)NB_BUCKETS * ARENA_CAP * 4);
    int*            ssrc   = (int*)alloc((size_t)N_EDGES * 4);
    int*            off    = (int*)alloc((size_t)(N_NODES + 1) * 4);
    unsigned*       gA     = (unsigned*)alloc((size_t)N_NODES * HID * 2);
    unsigned*       gB     = (unsigned*)alloc((size_t)N_NODES * HID * 2);
    unsigned short* Wt1    = (unsigned short*)alloc((size_t)64 * 128 * 2);
    unsigned short* Wt2    = (unsigned short*)alloc((size_t)64 * 64 * 2);
    unsigned short* Wt3    = (unsigned short*)alloc((size_t)64 * 64 * 2);
    float*          sums   = (float*)alloc((size_t)N_GRAPHS * HID * 4);
    (void)ws_size;

    const int TB = 256;
    int gridG = (N_NODES + 63) / 64;   // 64-row tiles (gemm / fused)
    int gridR = (N_NODES + 31) / 32;   // aggr: 32 rows per block

    // 1) preprocessing: arena bucketing -> CSR; weight transpose/cast
    hipMemsetAsync(bcount, 0, (size_t)NB_BUCKETS * 4, stream);
    hipMemsetAsync(sums, 0, (size_t)N_GRAPHS * HID * 4, stream);
    k_wprep<<<32, TB, 0, stream>>>(W1, W2, W3, Wt1, Wt2, Wt3);
    kb_scatter<<<NCHUNKS, TB, 0, stream>>>(esrc, edst, bcount, arena);
    kb_scan<<<1, 64, 0, stream>>>(bcount, bbase);
    k_bfin<<<NB_BUCKETS, TB, 0, stream>>>(arena, bbase, ssrc, off, dis);

    // 2) conv1 gemm: x @ W1 -> gA
    k_gemm<IN_DIM, true><<<gridG, TB, 0, stream>>>(x, Wt1, dis, gA);

    // 3) fused aggr1(relu,b1) + conv2 gemm -> gB
    k_aggr_gemm<<<gridG, TB, 0, stream>>>(gA, off, ssrc, dis, b1, Wt2, gB);

    // 4) fused aggr2(relu,b2) + conv3 gemm -> gA
    k_aggr_gemm<<<gridG, TB, 0, stream>>>(gB, off, ssrc, dis, b2, Wt3, gA);

    // 5) aggr3 (no relu) -> gB (bf16 h)
    k_aggr<false><<<gridR, TB, 0, stream>>>(gA, off, ssrc, dis, b3, gB);

    // 6) pool + classifier
    k_pool1<<<NB_BUCKETS, TB, 0, stream>>>((const unsigned short*)gB, batch, sums);
    k_cls<<<1, TB, 0, stream>>>(sums, batch, Wc1, bc1, Wc2, bc2, out);
}

// Round 13
// 302.481 us; speedup vs baseline: 1.4582x; 1.0603x over previous
//
#include <hip/hip_runtime.h>
#include <hip/hip_bf16.h>

#define N_NODES 100000
#define N_EDGES 1600000
#define IN_DIM 128
#define HID 64
#define N_GRAPHS 64
#define OUT_DIM 2

#define NB_BUCKETS ((N_NODES + 255) / 256)   // 391 buckets of 256 nodes
#define CHUNK 4096
#define NCHUNKS ((N_EDGES + CHUNK - 1) / CHUNK)  // 391
#define ARENA_CAP 6144   // per-bucket arena slots; mean 4092, sigma 64 -> +32 sigma

// ---------------- bf16 pack/unpack (RNE) ----------------

__device__ inline unsigned f2bf_rne(float f) {
    unsigned u = __float_as_uint(f);
    u += 0x7FFFu + ((u >> 16) & 1u);
    return u >> 16;
}
__device__ inline unsigned pack2(float lo, float hi) {
    return f2bf_rne(lo) | (f2bf_rne(hi) << 16);
}
__device__ inline float bf_lo(unsigned w) { return __uint_as_float(w << 16); }
__device__ inline float bf_hi(unsigned w) { return __uint_as_float(w & 0xFFFF0000u); }
__device__ inline float2 bf_pair(unsigned w) {
    return make_float2(bf_lo(w), bf_hi(w));
}
__device__ inline void acc2(float2& a, float2 b) { a.x += b.x; a.y += b.y; }
__device__ inline void accv(float2 a[4], uint4 v) {
    acc2(a[0], bf_pair(v.x)); acc2(a[1], bf_pair(v.y));
    acc2(a[2], bf_pair(v.z)); acc2(a[3], bf_pair(v.w));
}

// ---------------- edge bucketing (single-pass arena scatter) ----------------

__global__ void kb_scan(const int* __restrict__ bcount, int* __restrict__ bbase) {
    int lane = threadIdx.x;
    int carry = 0;
    for (int c = 0; c < (NB_BUCKETS + 63) / 64; ++c) {
        int idx = c * 64 + lane;
        int v = (idx < NB_BUCKETS) ? bcount[idx] : 0;
        int orig = v;
        for (int d = 1; d < 64; d <<= 1) {
            int u = __shfl_up(v, d);
            if (lane >= d) v += u;
        }
        if (idx < NB_BUCKETS) bbase[idx] = v - orig + carry;
        carry += __shfl(v, 63);
    }
    if (lane == 0) bbase[NB_BUCKETS] = carry;
}

__global__ __launch_bounds__(256) void kb_scatter(const int* __restrict__ src,
                                                  const int* __restrict__ dst,
                                                  int* __restrict__ bcount,
                                                  unsigned* __restrict__ arena) {
    __shared__ unsigned staged[CHUNK];            // 16 KB
    __shared__ unsigned short sbuck[CHUNK];       // 8 KB
    __shared__ int hist[NB_BUCKETS];
    __shared__ int lofs[NB_BUCKETS];
    __shared__ int lcur[NB_BUCKETS];
    __shared__ int gbase[NB_BUCKETS];
    int t = threadIdx.x;
    int lane = t & 63, wv = t >> 6;
    for (int i = t; i < NB_BUCKETS; i += 256) hist[i] = 0;
    __syncthreads();
    int chunk0 = blockIdx.x * CHUNK;
    int cN = min(CHUNK, N_EDGES - chunk0);
    for (int i = t; i < cN; i += 256) atomicAdd(&hist[dst[chunk0 + i] >> 8], 1);
    __syncthreads();
    if (wv == 0) {  // exclusive scan hist -> lofs
        int carry = 0;
        for (int c = 0; c < (NB_BUCKETS + 63) / 64; ++c) {
            int idx = c * 64 + lane;
            int v = (idx < NB_BUCKETS) ? hist[idx] : 0;
            int orig = v;
            for (int d = 1; d < 64; d <<= 1) {
                int u = __shfl_up(v, d);
                if (lane >= d) v += u;
            }
            if (idx < NB_BUCKETS) lofs[idx] = v - orig + carry;
            carry += __shfl(v, 63);
        }
    }
    __syncthreads();
    for (int i = t; i < NB_BUCKETS; i += 256) {
        lcur[i] = lofs[i];
        gbase[i] = hist[i] ? (atomicAdd(&bcount[i], hist[i]) + i * ARENA_CAP) : 0;
    }
    __syncthreads();
    for (int i = t; i < cN; i += 256) {  // stage bucket-major in LDS
        int e = chunk0 + i;
        int d = dst[e];
        int b = d >> 8;
        int lp = atomicAdd(&lcur[b], 1);
        staged[lp] = ((unsigned)src[e] << 8) | (unsigned)(d & 255);
        sbuck[lp] = (unsigned short)b;
    }
    __syncthreads();
    for (int p = t; p < cN; p += 256) {  // coalesced copy-out
        int b = sbuck[p];
        arena[gbase[b] + (p - lofs[b])] = staged[p];
    }
}

__global__ __launch_bounds__(256) void k_bfin(const unsigned* __restrict__ arena,
                                              const int* __restrict__ bbase,
                                              int* __restrict__ ssrc,
                                              int* __restrict__ off,
                                              float* __restrict__ dis) {
    __shared__ int cnt[256];
    __shared__ int lofs[256];
    __shared__ int lcur[256];
    int t = threadIdx.x;
    int lane = t & 63, wv = t >> 6;
    cnt[t] = 0;
    __syncthreads();
    int b = blockIdx.x;
    int lo = bbase[b];
    int cntB = bbase[b + 1] - lo;
    const unsigned* ap = arena + (size_t)b * ARENA_CAP;
    for (int e = t; e < cntB; e += 256) atomicAdd(&cnt[ap[e] & 255], 1);
    __syncthreads();
    if (wv == 0) {
        int carry = 0;
#pragma unroll
        for (int c = 0; c < 4; ++c) {
            int idx = c * 64 + lane;
            int v = cnt[idx];
            int orig = v;
            for (int d = 1; d < 64; d <<= 1) {
                int u = __shfl_up(v, d);
                if (lane >= d) v += u;
            }
            lofs[idx] = v - orig + carry;
            carry += __shfl(v, 63);
        }
    }
    __syncthreads();
    lcur[t] = lofs[t];
    int node = b * 256 + t;
    if (node < N_NODES) {
        off[node] = lo + lofs[t];
        dis[node] = rsqrtf((float)cnt[t] + 1.0f);  // +1 = self-loop
    }
    if (b == NB_BUCKETS - 1 && t == 0) off[N_NODES] = N_EDGES;
    __syncthreads();
    for (int e = t; e < cntB; e += 256) {
        unsigned pk = ap[e];
        int p = atomicAdd(&lcur[pk & 255u], 1);
        ssrc[lo + p] = (int)(pk >> 8);
    }
}

// ---------------- weight transpose + bf16 cast (once per launch) -----------

__global__ __launch_bounds__(256) void k_wprep(const float* __restrict__ W1,
                                               const float* __restrict__ W2,
                                               const float* __restrict__ W3,
                                               unsigned short* __restrict__ Wt1,
                                               unsigned short* __restrict__ Wt2,
                                               unsigned short* __restrict__ Wt3) {
    int t = blockIdx.x * 256 + threadIdx.x;
    if (t < 64 * 128) {  // Wt1[n][k] = bf16(W1[k][n]), n<64, k<128
        int n = t >> 7, k = t & 127;
        Wt1[t] = (unsigned short)f2bf_rne(W1[k * 64 + n]);
    }
    if (t < 64 * 64) {   // Wt2/Wt3[n][k], n<64, k<64
        int n = t >> 6, k = t & 63;
        Wt2[t] = (unsigned short)f2bf_rne(W2[k * 64 + n]);
        Wt3[t] = (unsigned short)f2bf_rne(W3[k * 64 + n]);
    }
}

// ---------------- conv1 GEMM: MFMA bf16, g16 = bf16(dis * A@W) --------------
template <int K, bool AF32>
__global__ __launch_bounds__(256) void k_gemm(const void* __restrict__ Ain,
                                              const unsigned short* __restrict__ Wt,
                                              const float* __restrict__ dis,
                                              unsigned* __restrict__ g16) {
    constexpr int PITCH = K + 8;  // shorts; keeps rows 16B-aligned
    constexpr int ABYTES = 2 * 64 * PITCH * 2;
    constexpr int CBYTES = 64 * 68 * 4;
    constexpr int SMEM = ABYTES > CBYTES ? ABYTES : CBYTES;
    __shared__ __align__(16) char smem[SMEM];
    short* As = (short*)smem;
    short* Bs = As + 64 * PITCH;
    float* Cs = (float*)smem;   // overlays As/Bs after MFMA phase
    constexpr int CP = 68;

    int t = threadIdx.x, lane = t & 63, w = t >> 6;
    int row0 = blockIdx.x * 64;

    constexpr int UN = 64 * (K / 8);  // 16B units per 64xK tile
#pragma unroll
    for (int u = t; u < UN; u += 256) {  // stage A (cast f32->bf16 if needed)
        int r = u / (K / 8), c = u % (K / 8);
        int grow = row0 + r;
        grow = grow < N_NODES ? grow : N_NODES - 1;
        uint4 o;
        if (AF32) {
            const float* Ap = (const float*)Ain + (size_t)grow * K + c * 8;
            float4 f0 = *(const float4*)Ap;
            float4 f1 = *(const float4*)(Ap + 4);
            o.x = pack2(f0.x, f0.y); o.y = pack2(f0.z, f0.w);
            o.z = pack2(f1.x, f1.y); o.w = pack2(f1.z, f1.w);
        } else {
            o = ((const uint4*)Ain)[(size_t)grow * (K / 8) + c];
        }
        *(uint4*)&As[r * PITCH + c * 8] = o;
    }
#pragma unroll
    for (int u = t; u < UN; u += 256) {  // stage B = Wt (already bf16, [n][K])
        int n = u / (K / 8), c = u % (K / 8);
        *(uint4*)&Bs[n * PITCH + c * 8] = *(const uint4*)&Wt[n * K + c * 8];
    }
    __syncthreads();

    using frag = __attribute__((ext_vector_type(8))) short;
    using fragc = __attribute__((ext_vector_type(4))) float;
    fragc z = {0.f, 0.f, 0.f, 0.f};
    fragc acc[4] = {z, z, z, z};
    int m = lane & 15, quad = lane >> 4;
#pragma unroll
    for (int ks = 0; ks < K / 32; ++ks) {
        frag a = *(frag*)&As[(w * 16 + m) * PITCH + ks * 32 + quad * 8];
#pragma unroll
        for (int nt = 0; nt < 4; ++nt) {
            frag b = *(frag*)&Bs[(nt * 16 + m) * PITCH + ks * 32 + quad * 8];
            acc[nt] = __builtin_amdgcn_mfma_f32_16x16x32_bf16(a, b, acc[nt], 0, 0, 0);
        }
    }
    __syncthreads();  // done reading As/Bs; reuse as Cs
#pragma unroll
    for (int nt = 0; nt < 4; ++nt)
#pragma unroll
        for (int reg = 0; reg < 4; ++reg)
            Cs[(w * 16 + quad * 4 + reg) * CP + nt * 16 + m] = acc[nt][reg];
    __syncthreads();

    {   // epilogue: thread -> (row, 16-col segment); scale by dis, pack bf16
        int r = t >> 2, c0 = (t & 3) * 16;
        int grow = row0 + r;
        if (grow < N_NODES) {
            float dr = dis[grow];
            const float* cp = &Cs[r * CP + c0];
            uint4 o0, o1;
            o0.x = pack2(cp[0] * dr, cp[1] * dr);
            o0.y = pack2(cp[2] * dr, cp[3] * dr);
            o0.z = pack2(cp[4] * dr, cp[5] * dr);
            o0.w = pack2(cp[6] * dr, cp[7] * dr);
            o1.x = pack2(cp[8] * dr, cp[9] * dr);
            o1.y = pack2(cp[10] * dr, cp[11] * dr);
            o1.z = pack2(cp[12] * dr, cp[13] * dr);
            o1.w = pack2(cp[14] * dr, cp[15] * dr);
            ((uint4*)g16)[(size_t)grow * 8 + (c0 >> 3)] = o0;
            ((uint4*)g16)[(size_t)grow * 8 + (c0 >> 3) + 1] = o1;
        }
    }
}

// ---------------- fused aggr + next-conv GEMM, 512 threads ------------------
// 8 waves; phase 1: each lane-group of 8 aggregates exactly ONE row into the
// LDS A-tile (bf16). Phase 2: 64x64 MFMA gemm split across 8 waves
// (16 rows x 32 cols each). Epilogue: gout = bf16(dis * .).
__global__ __launch_bounds__(512) void k_aggr_gemm(const unsigned* __restrict__ gin,
                                                   const int* __restrict__ off,
                                                   const int* __restrict__ ssrc,
                                                   const float* __restrict__ dis,
                                                   const float* __restrict__ bias,
                                                   const unsigned short* __restrict__ Wt,
                                                   unsigned* __restrict__ gout) {
    constexpr int K = HID;          // 64
    constexpr int PITCH = K + 8;    // 72 shorts
    constexpr int ABYTES = 2 * 64 * PITCH * 2;   // As + Bs
    constexpr int CBYTES = 64 * 68 * 4;
    constexpr int SMEM = ABYTES > CBYTES ? ABYTES : CBYTES;
    __shared__ __align__(16) char smem[SMEM];
    short* As = (short*)smem;
    short* Bs = As + 64 * PITCH;
    float* Cs = (float*)smem;
    constexpr int CP = 68;

    int t = threadIdx.x, lane = t & 63, w = t >> 6;
    int row0 = blockIdx.x * 64;
    int r8 = lane >> 3, li = lane & 7;
    const uint4* g4 = (const uint4*)gin;

    // stage B = Wt (512 threads -> exactly one uint4 each)
    {
        int n = t >> 3, c = t & 7;
        *(uint4*)&Bs[n * PITCH + c * 8] = *(const uint4*)&Wt[n * K + c * 8];
    }

    // phase 1: each lane-group of 8 aggregates one row into As
    {
        int r = w * 8 + r8;             // 0..63
        int row = row0 + r;
        int crow = row < N_NODES ? row : N_NODES - 1;
        float4 b0 = ((const float4*)bias)[li * 2];
        float4 b1 = ((const float4*)bias)[li * 2 + 1];
        float2 acc[4] = {make_float2(0.f, 0.f), make_float2(0.f, 0.f),
                         make_float2(0.f, 0.f), make_float2(0.f, 0.f)};
        int lo = off[crow], hi = off[crow + 1];
        int e = lo;
        for (; e + 3 < hi; e += 4) {  // 4 row-gathers in flight
            unsigned o0 = (unsigned)ssrc[e] * 8u + (unsigned)li;
            unsigned o1 = (unsigned)ssrc[e + 1] * 8u + (unsigned)li;
            unsigned o2 = (unsigned)ssrc[e + 2] * 8u + (unsigned)li;
            unsigned o3 = (unsigned)ssrc[e + 3] * 8u + (unsigned)li;
            uint4 v0 = g4[o0], v1 = g4[o1], v2 = g4[o2], v3 = g4[o3];
            accv(acc, v0); accv(acc, v1); accv(acc, v2); accv(acc, v3);
        }
        for (; e < hi; ++e) {
            uint4 v = g4[(unsigned)ssrc[e] * 8u + (unsigned)li];
            accv(acc, v);
        }
        uint4 sv = g4[(unsigned)crow * 8u + (unsigned)li];
        float2 sp[4] = {bf_pair(sv.x), bf_pair(sv.y), bf_pair(sv.z), bf_pair(sv.w)};
        float dr = dis[crow];
        float bb[8] = {b0.x, b0.y, b0.z, b0.w, b1.x, b1.y, b1.z, b1.w};
        float o[8];
#pragma unroll
        for (int j = 0; j < 4; ++j) {
            o[2 * j]     = fmaxf(dr * (acc[j].x + sp[j].x) + bb[2 * j], 0.f);
            o[2 * j + 1] = fmaxf(dr * (acc[j].y + sp[j].y) + bb[2 * j + 1], 0.f);
        }
        uint4 hv;
        hv.x = pack2(o[0], o[1]);
        hv.y = pack2(o[2], o[3]);
        hv.z = pack2(o[4], o[5]);
        hv.w = pack2(o[6], o[7]);
        *(uint4*)&As[r * PITCH + li * 8] = hv;
    }
    __syncthreads();

    // phase 2: MFMA gemm; wave w -> rows (w&3)*16..+16, cols (w>>2)*32..+32
    using frag = __attribute__((ext_vector_type(8))) short;
    using fragc = __attribute__((ext_vector_type(4))) float;
    fragc z = {0.f, 0.f, 0.f, 0.f};
    fragc acc[2] = {z, z};
    int m = lane & 15, quad = lane >> 4;
    int mt = w & 3, nh = w >> 2;
#pragma unroll
    for (int ks = 0; ks < K / 32; ++ks) {
        frag a = *(frag*)&As[(mt * 16 + m) * PITCH + ks * 32 + quad * 8];
#pragma unroll
        for (int n2 = 0; n2 < 2; ++n2) {
            int nt = nh * 2 + n2;
            frag b = *(frag*)&Bs[(nt * 16 + m) * PITCH + ks * 32 + quad * 8];
            acc[n2] = __builtin_amdgcn_mfma_f32_16x16x32_bf16(a, b, acc[n2], 0, 0, 0);
        }
    }
    __syncthreads();
#pragma unroll
    for (int n2 = 0; n2 < 2; ++n2)
#pragma unroll
        for (int reg = 0; reg < 4; ++reg)
            Cs[(mt * 16 + quad * 4 + reg) * CP + (nh * 2 + n2) * 16 + m] = acc[n2][reg];
    __syncthreads();
    {   // epilogue: 512 threads -> (row, 8-col segment)
        int r = t >> 3, c0 = (t & 7) * 8;
        int grow = row0 + r;
        if (grow < N_NODES) {
            float dr = dis[grow];
            const float* cp = &Cs[r * CP + c0];
            uint4 o;
            o.x = pack2(cp[0] * dr, cp[1] * dr);
            o.y = pack2(cp[2] * dr, cp[3] * dr);
            o.z = pack2(cp[4] * dr, cp[5] * dr);
            o.w = pack2(cp[6] * dr, cp[7] * dr);
            ((uint4*)gout)[(size_t)grow * 8 + (t & 7)] = o;
        }
    }
}

// ---------------- fused conv3-aggregate + mean-pool accumulate --------------
// Block = 32 rows. Computes o = dis*(self+sum)+b (no relu) per row, then
// LDS-accumulates per-graph sums (batch sorted -> 1-2 graphs/block) and
// flushes one global atomicAdd per (graph, feature).
__global__ __launch_bounds__(256) void k_aggr_pool(const unsigned* __restrict__ g16,
                                                   const int* __restrict__ off,
                                                   const int* __restrict__ ssrc,
                                                   const float* __restrict__ dis,
                                                   const float* __restrict__ bias,
                                                   const int* __restrict__ batch,
                                                   float* __restrict__ sums) {
    __shared__ float pacc[N_GRAPHS][HID];   // only [gmin..gmax] rows used
    int t = threadIdx.x;
    int lane = t & 63, wv = t >> 6;
    int r8 = lane >> 3, li = lane & 7;
    int row0 = blockIdx.x * 32;
    int row = row0 + wv * 8 + r8;
    bool valid = row < N_NODES;
    int gmin = batch[min(row0, N_NODES - 1)];
    int gmax = batch[min(row0 + 31, N_NODES - 1)];
    int gspan = gmax - gmin + 1;
    for (int idx = t; idx < gspan * HID; idx += 256)
        pacc[gmin + (idx >> 6)][idx & 63] = 0.f;
    __syncthreads();
    if (valid) {
        const uint4* g4 = (const uint4*)g16;
        float2 acc[4] = {make_float2(0.f, 0.f), make_float2(0.f, 0.f),
                         make_float2(0.f, 0.f), make_float2(0.f, 0.f)};
        int lo = off[row], hi = off[row + 1];
        int e = lo;
        for (; e + 3 < hi; e += 4) {
            unsigned o0 = (unsigned)ssrc[e] * 8u + (unsigned)li;
            unsigned o1 = (unsigned)ssrc[e + 1] * 8u + (unsigned)li;
            unsigned o2 = (unsigned)ssrc[e + 2] * 8u + (unsigned)li;
            unsigned o3 = (unsigned)ssrc[e + 3] * 8u + (unsigned)li;
            uint4 v0 = g4[o0], v1 = g4[o1], v2 = g4[o2], v3 = g4[o3];
            accv(acc, v0); accv(acc, v1); accv(acc, v2); accv(acc, v3);
        }
        for (; e < hi; ++e) {
            uint4 v = g4[(unsigned)ssrc[e] * 8u + (unsigned)li];
            accv(acc, v);
        }
        unsigned base = (unsigned)row * 8u + (unsigned)li;
        uint4 sv = g4[base];
        float2 sp[4] = {bf_pair(sv.x), bf_pair(sv.y), bf_pair(sv.z), bf_pair(sv.w)};
        float dr = dis[row];
        float4 b0 = ((const float4*)bias)[li * 2];
        float4 b1 = ((const float4*)bias)[li * 2 + 1];
        float bb[8] = {b0.x, b0.y, b0.z, b0.w, b1.x, b1.y, b1.z, b1.w};
        float* pg = &pacc[batch[row]][li * 8];
#pragma unroll
        for (int j = 0; j < 4; ++j) {
            atomicAdd(&pg[2 * j],     dr * (acc[j].x + sp[j].x) + bb[2 * j]);
            atomicAdd(&pg[2 * j + 1], dr * (acc[j].y + sp[j].y) + bb[2 * j + 1]);
        }
    }
    __syncthreads();
    for (int idx = t; idx < gspan * HID; idx += 256) {
        int g = gmin + (idx >> 6);
        atomicAdd(&sums[g * HID + (idx & 63)], pacc[g][idx & 63]);
    }
}

// ---------------- classifier ----------------

__device__ inline int lower_bound_batch(const int* batch, int key) {
    int lo = 0, hi = N_NODES;
    while (lo < hi) {
        int mid = (lo + hi) >> 1;
        if (batch[mid] < key) lo = mid + 1;
        else hi = mid;
    }
    return lo;
}

__global__ __launch_bounds__(256) void k_cls(const float* __restrict__ sums,
                                             const int* __restrict__ batch,
                                             const float* __restrict__ Wc1,
                                             const float* __restrict__ bc1,
                                             const float* __restrict__ Wc2,
                                             const float* __restrict__ bc2,
                                             float* __restrict__ out) {
    __shared__ float pooled[N_GRAPHS][HID];
    __shared__ float hc[N_GRAPHS][HID / 2];
    __shared__ float cnts[N_GRAPHS];
    int t = threadIdx.x;
    if (t < N_GRAPHS) {
        int lo = lower_bound_batch(batch, t);
        int hi = lower_bound_batch(batch, t + 1);
        cnts[t] = fmaxf((float)(hi - lo), 1.0f);
    }
    __syncthreads();
    for (int idx = t; idx < N_GRAPHS * HID; idx += 256) {
        int gi = idx >> 6;
        pooled[gi][idx & 63] = sums[idx] / cnts[gi];
    }
    __syncthreads();
    for (int idx = t; idx < N_GRAPHS * (HID / 2); idx += 256) {
        int gi = idx >> 5, f = idx & 31;
        float a = bc1[f];
#pragma unroll
        for (int k = 0; k < HID; ++k) a = fmaf(pooled[gi][k], Wc1[k * (HID / 2) + f], a);
        hc[gi][f] = fmaxf(a, 0.f);
    }
    __syncthreads();
    for (int idx = t; idx < N_GRAPHS * OUT_DIM; idx += 256) {
        int gi = idx >> 1, f = idx & 1;
        float a = bc2[f];
#pragma unroll
        for (int k = 0; k < HID / 2; ++k) a = fmaf(hc[gi][k], Wc2[k * OUT_DIM + f], a);
        out[gi * OUT_DIM + f] = a;
    }
}

// ---------------- launch ----------------

extern "C" void kernel_launch(void* const* d_in, const int* in_sizes, int n_in,
                              void* d_out, int out_size, void* d_ws, size_t ws_size,
                              hipStream_t stream) {
    const float* x    = (const float*)d_in[0];
    const int*   eidx = (const int*)d_in[1];
    const int*   batch= (const int*)d_in[2];
    const float* W1 = (const float*)d_in[3];  const float* b1 = (const float*)d_in[4];
    const float* W2 = (const float*)d_in[5];  const float* b2 = (const float*)d_in[6];
    const float* W3 = (const float*)d_in[7];  const float* b3 = (const float*)d_in[8];
    const float* Wc1 = (const float*)d_in[9];  const float* bc1 = (const float*)d_in[10];
    const float* Wc2 = (const float*)d_in[11]; const float* bc2 = (const float*)d_in[12];
    float* out = (float*)d_out;

    const int* esrc = eidx;
    const int* edst = eidx + N_EDGES;

    size_t o = 0;
    auto alloc = [&](size_t bytes) {
        void* p = (char*)d_ws + o;
        o += (bytes + 255) & ~(size_t)255;
        return p;
    };
    int*            bcount = (int*)alloc((size_t)NB_BUCKETS * 4);
    int*            bbase  = (int*)alloc((size_t)(NB_BUCKETS + 1) * 4);
    float*          dis    = (float*)alloc((size_t)N_NODES * 4);
    unsigned*       arena  = (unsigned*)alloc((size_t)NB_BUCKETS * ARENA_CAP * 4);
    int*            ssrc   = (int*)alloc((size_t)N_EDGES * 4);
    int*            off    = (int*)alloc((size_t)(N_NODES + 1) * 4);
    unsigned*       gA     = (unsigned*)alloc((size_t)N_NODES * HID * 2);
    unsigned*       gB     = (unsigned*)alloc((size_t)N_NODES * HID * 2);
    unsigned short* Wt1    = (unsigned short*)alloc((size_t)64 * 128 * 2);
    unsigned short* Wt2    = (unsigned short*)alloc((size_t)64 * 64 * 2);
    unsigned short* Wt3    = (unsigned short*)alloc((size_t)64 * 64 * 2);
    float*          sums   = (float*)alloc((size_t)N_GRAPHS * HID * 4);
    (void)ws_size;

    const int TB = 256;
    int gridG = (N_NODES + 63) / 64;   // 64-row tiles (gemm / fused)
    int gridP = (N_NODES + 31) / 32;   // aggr_pool: 32 rows per block

    // 1) preprocessing: arena bucketing -> CSR; weight transpose/cast
    hipMemsetAsync(bcount, 0, (size_t)NB_BUCKETS * 4, stream);
    hipMemsetAsync(sums, 0, (size_t)N_GRAPHS * HID * 4, stream);
    k_wprep<<<32, TB, 0, stream>>>(W1, W2, W3, Wt1, Wt2, Wt3);
    kb_scatter<<<NCHUNKS, TB, 0, stream>>>(esrc, edst, bcount, arena);
    kb_scan<<<1, 64, 0, stream>>>(bcount, bbase);
    k_bfin<<<NB_BUCKETS, TB, 0, stream>>>(arena, bbase, ssrc, off, dis);

    // 2) conv1 gemm: x @ W1 -> gA
    k_gemm<IN_DIM, true><<<gridG, TB, 0, stream>>>(x, Wt1, dis, gA);

    // 3) fused aggr1(relu,b1) + conv2 gemm -> gB  (512-thread)
    k_aggr_gemm<<<gridG, 512, 0, stream>>>(gA, off, ssrc, dis, b1, Wt2, gB);

    // 4) fused aggr2(relu,b2) + conv3 gemm -> gA  (512-thread)
    k_aggr_gemm<<<gridG, 512, 0, stream>>>(gB, off, ssrc, dis, b2, Wt3, gA);

    // 5) fused aggr3 (no relu) + mean-pool accumulate -> sums
    k_aggr_pool<<<gridP, TB, 0, stream>>>(gA, off, ssrc, dis, b3, batch, sums);

    // 6) classifier
    k_cls<<<1, TB, 0, stream>>>(sums, batch, Wc1, bc1, Wc2, bc2, out);
}

// Round 14
// 277.371 us; speedup vs baseline: 1.5902x; 1.0905x over previous
//
#include <hip/hip_runtime.h>
#include <hip/hip_bf16.h>

#define N_NODES 100000
#define N_EDGES 1600000
#define IN_DIM 128
#define HID 64
#define N_GRAPHS 64
#define OUT_DIM 2

#define NB_BUCKETS ((N_NODES + 255) / 256)   // 391 buckets of 256 nodes
#define CHUNK 4096
#define NCHUNKS ((N_EDGES + CHUNK - 1) / CHUNK)  // 391
#define ARENA_CAP 6144   // per-bucket arena slots; mean 4092, sigma 64 -> +32 sigma

// ---------------- bf16 pack/unpack (RNE) ----------------

__device__ inline unsigned f2bf_rne(float f) {
    unsigned u = __float_as_uint(f);
    u += 0x7FFFu + ((u >> 16) & 1u);
    return u >> 16;
}
__device__ inline unsigned pack2(float lo, float hi) {
    return f2bf_rne(lo) | (f2bf_rne(hi) << 16);
}
__device__ inline float bf_lo(unsigned w) { return __uint_as_float(w << 16); }
__device__ inline float bf_hi(unsigned w) { return __uint_as_float(w & 0xFFFF0000u); }
__device__ inline float2 bf_pair(unsigned w) {
    return make_float2(bf_lo(w), bf_hi(w));
}
__device__ inline void acc2(float2& a, float2 b) { a.x += b.x; a.y += b.y; }
__device__ inline void accv(float2 a[4], uint4 v) {
    acc2(a[0], bf_pair(v.x)); acc2(a[1], bf_pair(v.y));
    acc2(a[2], bf_pair(v.z)); acc2(a[3], bf_pair(v.w));
}

// ---------------- edge bucketing (single-pass arena scatter) ----------------

__global__ void kb_scan(const int* __restrict__ bcount, int* __restrict__ bbase) {
    int lane = threadIdx.x;
    int carry = 0;
    for (int c = 0; c < (NB_BUCKETS + 63) / 64; ++c) {
        int idx = c * 64 + lane;
        int v = (idx < NB_BUCKETS) ? bcount[idx] : 0;
        int orig = v;
        for (int d = 1; d < 64; d <<= 1) {
            int u = __shfl_up(v, d);
            if (lane >= d) v += u;
        }
        if (idx < NB_BUCKETS) bbase[idx] = v - orig + carry;
        carry += __shfl(v, 63);
    }
    if (lane == 0) bbase[NB_BUCKETS] = carry;
}

__global__ __launch_bounds__(256) void kb_scatter(const int* __restrict__ src,
                                                  const int* __restrict__ dst,
                                                  int* __restrict__ bcount,
                                                  unsigned* __restrict__ arena) {
    __shared__ unsigned staged[CHUNK];            // 16 KB
    __shared__ unsigned short sbuck[CHUNK];       // 8 KB
    __shared__ int hist[NB_BUCKETS];
    __shared__ int lofs[NB_BUCKETS];
    __shared__ int lcur[NB_BUCKETS];
    __shared__ int gbase[NB_BUCKETS];
    int t = threadIdx.x;
    int lane = t & 63, wv = t >> 6;
    for (int i = t; i < NB_BUCKETS; i += 256) hist[i] = 0;
    __syncthreads();
    int chunk0 = blockIdx.x * CHUNK;
    int cN = min(CHUNK, N_EDGES - chunk0);
    for (int i = t; i < cN; i += 256) atomicAdd(&hist[dst[chunk0 + i] >> 8], 1);
    __syncthreads();
    if (wv == 0) {  // exclusive scan hist -> lofs
        int carry = 0;
        for (int c = 0; c < (NB_BUCKETS + 63) / 64; ++c) {
            int idx = c * 64 + lane;
            int v = (idx < NB_BUCKETS) ? hist[idx] : 0;
            int orig = v;
            for (int d = 1; d < 64; d <<= 1) {
                int u = __shfl_up(v, d);
                if (lane >= d) v += u;
            }
            if (idx < NB_BUCKETS) lofs[idx] = v - orig + carry;
            carry += __shfl(v, 63);
        }
    }
    __syncthreads();
    for (int i = t; i < NB_BUCKETS; i += 256) {
        lcur[i] = lofs[i];
        gbase[i] = hist[i] ? (atomicAdd(&bcount[i], hist[i]) + i * ARENA_CAP) : 0;
    }
    __syncthreads();
    for (int i = t; i < cN; i += 256) {  // stage bucket-major in LDS
        int e = chunk0 + i;
        int d = dst[e];
        int b = d >> 8;
        int lp = atomicAdd(&lcur[b], 1);
        staged[lp] = ((unsigned)src[e] << 8) | (unsigned)(d & 255);
        sbuck[lp] = (unsigned short)b;
    }
    __syncthreads();
    for (int p = t; p < cN; p += 256) {  // coalesced copy-out
        int b = sbuck[p];
        arena[gbase[b] + (p - lofs[b])] = staged[p];
    }
}

__global__ __launch_bounds__(256) void k_bfin(const unsigned* __restrict__ arena,
                                              const int* __restrict__ bbase,
                                              int* __restrict__ ssrc,
                                              int* __restrict__ off,
                                              float* __restrict__ dis) {
    __shared__ int cnt[256];
    __shared__ int lofs[256];
    __shared__ int lcur[256];
    int t = threadIdx.x;
    int lane = t & 63, wv = t >> 6;
    cnt[t] = 0;
    __syncthreads();
    int b = blockIdx.x;
    int lo = bbase[b];
    int cntB = bbase[b + 1] - lo;
    const unsigned* ap = arena + (size_t)b * ARENA_CAP;
    for (int e = t; e < cntB; e += 256) atomicAdd(&cnt[ap[e] & 255], 1);
    __syncthreads();
    if (wv == 0) {
        int carry = 0;
#pragma unroll
        for (int c = 0; c < 4; ++c) {
            int idx = c * 64 + lane;
            int v = cnt[idx];
            int orig = v;
            for (int d = 1; d < 64; d <<= 1) {
                int u = __shfl_up(v, d);
                if (lane >= d) v += u;
            }
            lofs[idx] = v - orig + carry;
            carry += __shfl(v, 63);
        }
    }
    __syncthreads();
    lcur[t] = lofs[t];
    int node = b * 256 + t;
    if (node < N_NODES) {
        off[node] = lo + lofs[t];
        dis[node] = rsqrtf((float)cnt[t] + 1.0f);  // +1 = self-loop
    }
    if (b == NB_BUCKETS - 1 && t == 0) off[N_NODES] = N_EDGES;
    __syncthreads();
    for (int e = t; e < cntB; e += 256) {
        unsigned pk = ap[e];
        int p = atomicAdd(&lcur[pk & 255u], 1);
        ssrc[lo + p] = (int)(pk >> 8);
    }
}

// ---------------- weight transpose + bf16 cast (once per launch) -----------

__global__ __launch_bounds__(256) void k_wprep(const float* __restrict__ W1,
                                               const float* __restrict__ W2,
                                               const float* __restrict__ W3,
                                               unsigned short* __restrict__ Wt1,
                                               unsigned short* __restrict__ Wt2,
                                               unsigned short* __restrict__ Wt3) {
    int t = blockIdx.x * 256 + threadIdx.x;
    if (t < 64 * 128) {  // Wt1[n][k] = bf16(W1[k][n]), n<64, k<128
        int n = t >> 7, k = t & 127;
        Wt1[t] = (unsigned short)f2bf_rne(W1[k * 64 + n]);
    }
    if (t < 64 * 64) {   // Wt2/Wt3[n][k], n<64, k<64
        int n = t >> 6, k = t & 63;
        Wt2[t] = (unsigned short)f2bf_rne(W2[k * 64 + n]);
        Wt3[t] = (unsigned short)f2bf_rne(W3[k * 64 + n]);
    }
}

// ---------------- conv1 GEMM: MFMA bf16, g16 = bf16(dis * A@W) --------------
template <int K, bool AF32>
__global__ __launch_bounds__(256) void k_gemm(const void* __restrict__ Ain,
                                              const unsigned short* __restrict__ Wt,
                                              const float* __restrict__ dis,
                                              unsigned* __restrict__ g16) {
    constexpr int PITCH = K + 8;  // shorts; keeps rows 16B-aligned
    constexpr int ABYTES = 2 * 64 * PITCH * 2;
    constexpr int CBYTES = 64 * 68 * 4;
    constexpr int SMEM = ABYTES > CBYTES ? ABYTES : CBYTES;
    __shared__ __align__(16) char smem[SMEM];
    short* As = (short*)smem;
    short* Bs = As + 64 * PITCH;
    float* Cs = (float*)smem;   // overlays As/Bs after MFMA phase
    constexpr int CP = 68;

    int t = threadIdx.x, lane = t & 63, w = t >> 6;
    int row0 = blockIdx.x * 64;

    constexpr int UN = 64 * (K / 8);  // 16B units per 64xK tile
#pragma unroll
    for (int u = t; u < UN; u += 256) {  // stage A (cast f32->bf16 if needed)
        int r = u / (K / 8), c = u % (K / 8);
        int grow = row0 + r;
        grow = grow < N_NODES ? grow : N_NODES - 1;
        uint4 o;
        if (AF32) {
            const float* Ap = (const float*)Ain + (size_t)grow * K + c * 8;
            float4 f0 = *(const float4*)Ap;
            float4 f1 = *(const float4*)(Ap + 4);
            o.x = pack2(f0.x, f0.y); o.y = pack2(f0.z, f0.w);
            o.z = pack2(f1.x, f1.y); o.w = pack2(f1.z, f1.w);
        } else {
            o = ((const uint4*)Ain)[(size_t)grow * (K / 8) + c];
        }
        *(uint4*)&As[r * PITCH + c * 8] = o;
    }
#pragma unroll
    for (int u = t; u < UN; u += 256) {  // stage B = Wt (already bf16, [n][K])
        int n = u / (K / 8), c = u % (K / 8);
        *(uint4*)&Bs[n * PITCH + c * 8] = *(const uint4*)&Wt[n * K + c * 8];
    }
    __syncthreads();

    using frag = __attribute__((ext_vector_type(8))) short;
    using fragc = __attribute__((ext_vector_type(4))) float;
    fragc z = {0.f, 0.f, 0.f, 0.f};
    fragc acc[4] = {z, z, z, z};
    int m = lane & 15, quad = lane >> 4;
#pragma unroll
    for (int ks = 0; ks < K / 32; ++ks) {
        frag a = *(frag*)&As[(w * 16 + m) * PITCH + ks * 32 + quad * 8];
#pragma unroll
        for (int nt = 0; nt < 4; ++nt) {
            frag b = *(frag*)&Bs[(nt * 16 + m) * PITCH + ks * 32 + quad * 8];
            acc[nt] = __builtin_amdgcn_mfma_f32_16x16x32_bf16(a, b, acc[nt], 0, 0, 0);
        }
    }
    __syncthreads();  // done reading As/Bs; reuse as Cs
#pragma unroll
    for (int nt = 0; nt < 4; ++nt)
#pragma unroll
        for (int reg = 0; reg < 4; ++reg)
            Cs[(w * 16 + quad * 4 + reg) * CP + nt * 16 + m] = acc[nt][reg];
    __syncthreads();

    {   // epilogue: thread -> (row, 16-col segment); scale by dis, pack bf16
        int r = t >> 2, c0 = (t & 3) * 16;
        int grow = row0 + r;
        if (grow < N_NODES) {
            float dr = dis[grow];
            const float* cp = &Cs[r * CP + c0];
            uint4 o0, o1;
            o0.x = pack2(cp[0] * dr, cp[1] * dr);
            o0.y = pack2(cp[2] * dr, cp[3] * dr);
            o0.z = pack2(cp[4] * dr, cp[5] * dr);
            o0.w = pack2(cp[6] * dr, cp[7] * dr);
            o1.x = pack2(cp[8] * dr, cp[9] * dr);
            o1.y = pack2(cp[10] * dr, cp[11] * dr);
            o1.z = pack2(cp[12] * dr, cp[13] * dr);
            o1.w = pack2(cp[14] * dr, cp[15] * dr);
            ((uint4*)g16)[(size_t)grow * 8 + (c0 >> 3)] = o0;
            ((uint4*)g16)[(size_t)grow * 8 + (c0 >> 3) + 1] = o1;
        }
    }
}

// ---------------- fused aggr + next-conv GEMM, 512 threads ------------------
__global__ __launch_bounds__(512) void k_aggr_gemm(const unsigned* __restrict__ gin,
                                                   const int* __restrict__ off,
                                                   const int* __restrict__ ssrc,
                                                   const float* __restrict__ dis,
                                                   const float* __restrict__ bias,
                                                   const unsigned short* __restrict__ Wt,
                                                   unsigned* __restrict__ gout) {
    constexpr int K = HID;          // 64
    constexpr int PITCH = K + 8;    // 72 shorts
    constexpr int ABYTES = 2 * 64 * PITCH * 2;   // As + Bs
    constexpr int CBYTES = 64 * 68 * 4;
    constexpr int SMEM = ABYTES > CBYTES ? ABYTES : CBYTES;
    __shared__ __align__(16) char smem[SMEM];
    short* As = (short*)smem;
    short* Bs = As + 64 * PITCH;
    float* Cs = (float*)smem;
    constexpr int CP = 68;

    int t = threadIdx.x, lane = t & 63, w = t >> 6;
    int row0 = blockIdx.x * 64;
    int r8 = lane >> 3, li = lane & 7;
    const uint4* g4 = (const uint4*)gin;

    // stage B = Wt (512 threads -> exactly one uint4 each)
    {
        int n = t >> 3, c = t & 7;
        *(uint4*)&Bs[n * PITCH + c * 8] = *(const uint4*)&Wt[n * K + c * 8];
    }

    // phase 1: each lane-group of 8 aggregates one row into As
    {
        int r = w * 8 + r8;             // 0..63
        int row = row0 + r;
        int crow = row < N_NODES ? row : N_NODES - 1;
        float4 b0 = ((const float4*)bias)[li * 2];
        float4 b1 = ((const float4*)bias)[li * 2 + 1];
        float2 acc[4] = {make_float2(0.f, 0.f), make_float2(0.f, 0.f),
                         make_float2(0.f, 0.f), make_float2(0.f, 0.f)};
        int lo = off[crow], hi = off[crow + 1];
        int e = lo;
        for (; e + 3 < hi; e += 4) {  // 4 row-gathers in flight
            unsigned o0 = (unsigned)ssrc[e] * 8u + (unsigned)li;
            unsigned o1 = (unsigned)ssrc[e + 1] * 8u + (unsigned)li;
            unsigned o2 = (unsigned)ssrc[e + 2] * 8u + (unsigned)li;
            unsigned o3 = (unsigned)ssrc[e + 3] * 8u + (unsigned)li;
            uint4 v0 = g4[o0], v1 = g4[o1], v2 = g4[o2], v3 = g4[o3];
            accv(acc, v0); accv(acc, v1); accv(acc, v2); accv(acc, v3);
        }
        for (; e < hi; ++e) {
            uint4 v = g4[(unsigned)ssrc[e] * 8u + (unsigned)li];
            accv(acc, v);
        }
        uint4 sv = g4[(unsigned)crow * 8u + (unsigned)li];
        float2 sp[4] = {bf_pair(sv.x), bf_pair(sv.y), bf_pair(sv.z), bf_pair(sv.w)};
        float dr = dis[crow];
        float bb[8] = {b0.x, b0.y, b0.z, b0.w, b1.x, b1.y, b1.z, b1.w};
        float o[8];
#pragma unroll
        for (int j = 0; j < 4; ++j) {
            o[2 * j]     = fmaxf(dr * (acc[j].x + sp[j].x) + bb[2 * j], 0.f);
            o[2 * j + 1] = fmaxf(dr * (acc[j].y + sp[j].y) + bb[2 * j + 1], 0.f);
        }
        uint4 hv;
        hv.x = pack2(o[0], o[1]);
        hv.y = pack2(o[2], o[3]);
        hv.z = pack2(o[4], o[5]);
        hv.w = pack2(o[6], o[7]);
        *(uint4*)&As[r * PITCH + li * 8] = hv;
    }
    __syncthreads();

    // phase 2: MFMA gemm; wave w -> rows (w&3)*16..+16, cols (w>>2)*32..+32
    using frag = __attribute__((ext_vector_type(8))) short;
    using fragc = __attribute__((ext_vector_type(4))) float;
    fragc z = {0.f, 0.f, 0.f, 0.f};
    fragc acc[2] = {z, z};
    int m = lane & 15, quad = lane >> 4;
    int mt = w & 3, nh = w >> 2;
#pragma unroll
    for (int ks = 0; ks < K / 32; ++ks) {
        frag a = *(frag*)&As[(mt * 16 + m) * PITCH + ks * 32 + quad * 8];
#pragma unroll
        for (int n2 = 0; n2 < 2; ++n2) {
            int nt = nh * 2 + n2;
            frag b = *(frag*)&Bs[(nt * 16 + m) * PITCH + ks * 32 + quad * 8];
            acc[n2] = __builtin_amdgcn_mfma_f32_16x16x32_bf16(a, b, acc[n2], 0, 0, 0);
        }
    }
    __syncthreads();
#pragma unroll
    for (int n2 = 0; n2 < 2; ++n2)
#pragma unroll
        for (int reg = 0; reg < 4; ++reg)
            Cs[(mt * 16 + quad * 4 + reg) * CP + (nh * 2 + n2) * 16 + m] = acc[n2][reg];
    __syncthreads();
    {   // epilogue: 512 threads -> (row, 8-col segment)
        int r = t >> 3, c0 = (t & 7) * 8;
        int grow = row0 + r;
        if (grow < N_NODES) {
            float dr = dis[grow];
            const float* cp = &Cs[r * CP + c0];
            uint4 o;
            o.x = pack2(cp[0] * dr, cp[1] * dr);
            o.y = pack2(cp[2] * dr, cp[3] * dr);
            o.z = pack2(cp[4] * dr, cp[5] * dr);
            o.w = pack2(cp[6] * dr, cp[7] * dr);
            ((uint4*)gout)[(size_t)grow * 8 + (t & 7)] = o;
        }
    }
}

// ---------------- fused conv3-aggregate + mean-pool accumulate --------------
// Block = 32 rows. Each lane-group writes its row result to a PRIVATE LDS
// slot (no atomics), then lanes 0..63 sweep the 32 rows run-accumulating per
// graph (batch sorted) and flush one global atomic per (transition, feature).
__global__ __launch_bounds__(256) void k_aggr_pool(const unsigned* __restrict__ g16,
                                                   const int* __restrict__ off,
                                                   const int* __restrict__ ssrc,
                                                   const float* __restrict__ dis,
                                                   const float* __restrict__ bias,
                                                   const int* __restrict__ batch,
                                                   float* __restrict__ sums) {
    __shared__ float rowres[32][HID];   // 8 KB, per-row private slots
    __shared__ int sgid[32];
    int t = threadIdx.x;
    int lane = t & 63, wv = t >> 6;
    int r8 = lane >> 3, li = lane & 7;
    int r = wv * 8 + r8;                // 0..31
    int row = blockIdx.x * 32 + r;
    bool valid = row < N_NODES;
    if (li == 0) sgid[r] = valid ? batch[row] : -1;
    if (valid) {
        const uint4* g4 = (const uint4*)g16;
        float2 acc[4] = {make_float2(0.f, 0.f), make_float2(0.f, 0.f),
                         make_float2(0.f, 0.f), make_float2(0.f, 0.f)};
        int lo = off[row], hi = off[row + 1];
        int e = lo;
        for (; e + 3 < hi; e += 4) {
            unsigned o0 = (unsigned)ssrc[e] * 8u + (unsigned)li;
            unsigned o1 = (unsigned)ssrc[e + 1] * 8u + (unsigned)li;
            unsigned o2 = (unsigned)ssrc[e + 2] * 8u + (unsigned)li;
            unsigned o3 = (unsigned)ssrc[e + 3] * 8u + (unsigned)li;
            uint4 v0 = g4[o0], v1 = g4[o1], v2 = g4[o2], v3 = g4[o3];
            accv(acc, v0); accv(acc, v1); accv(acc, v2); accv(acc, v3);
        }
        for (; e < hi; ++e) {
            uint4 v = g4[(unsigned)ssrc[e] * 8u + (unsigned)li];
            accv(acc, v);
        }
        unsigned base = (unsigned)row * 8u + (unsigned)li;
        uint4 sv = g4[base];
        float2 sp[4] = {bf_pair(sv.x), bf_pair(sv.y), bf_pair(sv.z), bf_pair(sv.w)};
        float dr = dis[row];
        float4 b0 = ((const float4*)bias)[li * 2];
        float4 b1 = ((const float4*)bias)[li * 2 + 1];
        float bb[8] = {b0.x, b0.y, b0.z, b0.w, b1.x, b1.y, b1.z, b1.w};
        float* pr = &rowres[r][li * 8];
        float4 o0, o1;
        o0.x = dr * (acc[0].x + sp[0].x) + bb[0];
        o0.y = dr * (acc[0].y + sp[0].y) + bb[1];
        o0.z = dr * (acc[1].x + sp[1].x) + bb[2];
        o0.w = dr * (acc[1].y + sp[1].y) + bb[3];
        o1.x = dr * (acc[2].x + sp[2].x) + bb[4];
        o1.y = dr * (acc[2].y + sp[2].y) + bb[5];
        o1.z = dr * (acc[3].x + sp[3].x) + bb[6];
        o1.w = dr * (acc[3].y + sp[3].y) + bb[7];
        *(float4*)pr = o0;
        *(float4*)(pr + 4) = o1;
    }
    __syncthreads();
    if (t < HID) {  // lanes 0..63: run-accumulate rows per graph, flush at edges
        float acc = 0.f;
        int cur = -1;
        for (int r2 = 0; r2 < 32; ++r2) {
            int g = sgid[r2];
            if (g < 0) break;
            if (g != cur) {
                if (cur >= 0) atomicAdd(&sums[cur * HID + t], acc);
                acc = 0.f;
                cur = g;
            }
            acc += rowres[r2][t];
        }
        if (cur >= 0) atomicAdd(&sums[cur * HID + t], acc);
    }
}

// ---------------- classifier ----------------

__device__ inline int lower_bound_batch(const int* batch, int key) {
    int lo = 0, hi = N_NODES;
    while (lo < hi) {
        int mid = (lo + hi) >> 1;
        if (batch[mid] < key) lo = mid + 1;
        else hi = mid;
    }
    return lo;
}

__global__ __launch_bounds__(256) void k_cls(const float* __restrict__ sums,
                                             const int* __restrict__ batch,
                                             const float* __restrict__ Wc1,
                                             const float* __restrict__ bc1,
                                             const float* __restrict__ Wc2,
                                             const float* __restrict__ bc2,
                                             float* __restrict__ out) {
    __shared__ float pooled[N_GRAPHS][HID];
    __shared__ float hc[N_GRAPHS][HID / 2];
    __shared__ float cnts[N_GRAPHS];
    int t = threadIdx.x;
    if (t < N_GRAPHS) {
        int lo = lower_bound_batch(batch, t);
        int hi = lower_bound_batch(batch, t + 1);
        cnts[t] = fmaxf((float)(hi - lo), 1.0f);
    }
    __syncthreads();
    for (int idx = t; idx < N_GRAPHS * HID; idx += 256) {
        int gi = idx >> 6;
        pooled[gi][idx & 63] = sums[idx] / cnts[gi];
    }
    __syncthreads();
    for (int idx = t; idx < N_GRAPHS * (HID / 2); idx += 256) {
        int gi = idx >> 5, f = idx & 31;
        float a = bc1[f];
#pragma unroll
        for (int k = 0; k < HID; ++k) a = fmaf(pooled[gi][k], Wc1[k * (HID / 2) + f], a);
        hc[gi][f] = fmaxf(a, 0.f);
    }
    __syncthreads();
    for (int idx = t; idx < N_GRAPHS * OUT_DIM; idx += 256) {
        int gi = idx >> 1, f = idx & 1;
        float a = bc2[f];
#pragma unroll
        for (int k = 0; k < HID / 2; ++k) a = fmaf(hc[gi][k], Wc2[k * OUT_DIM + f], a);
        out[gi * OUT_DIM + f] = a;
    }
}

// ---------------- launch ----------------

extern "C" void kernel_launch(void* const* d_in, const int* in_sizes, int n_in,
                              void* d_out, int out_size, void* d_ws, size_t ws_size,
                              hipStream_t stream) {
    const float* x    = (const float*)d_in[0];
    const int*   eidx = (const int*)d_in[1];
    const int*   batch= (const int*)d_in[2];
    const float* W1 = (const float*)d_in[3];  const float* b1 = (const float*)d_in[4];
    const float* W2 = (const float*)d_in[5];  const float* b2 = (const float*)d_in[6];
    const float* W3 = (const float*)d_in[7];  const float* b3 = (const float*)d_in[8];
    const float* Wc1 = (const float*)d_in[9];  const float* bc1 = (const float*)d_in[10];
    const float* Wc2 = (const float*)d_in[11]; const float* bc2 = (const float*)d_in[12];
    float* out = (float*)d_out;

    const int* esrc = eidx;
    const int* edst = eidx + N_EDGES;

    size_t o = 0;
    auto alloc = [&](size_t bytes) {
        void* p = (char*)d_ws + o;
        o += (bytes + 255) & ~(size_t)255;
        return p;
    };
    int*            bcount = (int*)alloc((size_t)NB_BUCKETS * 4);
    int*            bbase  = (int*)alloc((size_t)(NB_BUCKETS + 1) * 4);
    float*          dis    = (float*)alloc((size_t)N_NODES * 4);
    unsigned*       arena  = (unsigned*)alloc((size_t)NB_BUCKETS * ARENA_CAP * 4);
    int*            ssrc   = (int*)alloc((size_t)N_EDGES * 4);
    int*            off    = (int*)alloc((size_t)(N_NODES + 1) * 4);
    unsigned*       gA     = (unsigned*)alloc((size_t)N_NODES * HID * 2);
    unsigned*       gB     = (unsigned*)alloc((size_t)N_NODES * HID * 2);
    unsigned short* Wt1    = (unsigned short*)alloc((size_t)64 * 128 * 2);
    unsigned short* Wt2    = (unsigned short*)alloc((size_t)64 * 64 * 2);
    unsigned short* Wt3    = (unsigned short*)alloc((size_t)64 * 64 * 2);
    float*          sums   = (float*)alloc((size_t)N_GRAPHS * HID * 4);
    (void)ws_size;

    const int TB = 256;
    int gridG = (N_NODES + 63) / 64;   // 64-row tiles (gemm / fused)
    int gridP = (N_NODES + 31) / 32;   // aggr_pool: 32 rows per block

    // 1) preprocessing: arena bucketing -> CSR; weight transpose/cast
    hipMemsetAsync(bcount, 0, (size_t)NB_BUCKETS * 4, stream);
    hipMemsetAsync(sums, 0, (size_t)N_GRAPHS * HID * 4, stream);
    k_wprep<<<32, TB, 0, stream>>>(W1, W2, W3, Wt1, Wt2, Wt3);
    kb_scatter<<<NCHUNKS, TB, 0, stream>>>(esrc, edst, bcount, arena);
    kb_scan<<<1, 64, 0, stream>>>(bcount, bbase);
    k_bfin<<<NB_BUCKETS, TB, 0, stream>>>(arena, bbase, ssrc, off, dis);

    // 2) conv1 gemm: x @ W1 -> gA
    k_gemm<IN_DIM, true><<<gridG, TB, 0, stream>>>(x, Wt1, dis, gA);

    // 3) fused aggr1(relu,b1) + conv2 gemm -> gB  (512-thread)
    k_aggr_gemm<<<gridG, 512, 0, stream>>>(gA, off, ssrc, dis, b1, Wt2, gB);

    // 4) fused aggr2(relu,b2) + conv3 gemm -> gA  (512-thread)
    k_aggr_gemm<<<gridG, 512, 0, stream>>>(gB, off, ssrc, dis, b2, Wt3, gA);

    // 5) fused aggr3 (no relu) + mean-pool accumulate -> sums
    k_aggr_pool<<<gridP, TB, 0, stream>>>(gA, off, ssrc, dis, b3, batch, sums);

    // 6) classifier
    k_cls<<<1, TB, 0, stream>>>(sums, batch, Wc1, bc1, Wc2, bc2, out);
}